// Round 1
// baseline (3420.184 us; speedup 1.0000x reference)
//
#include <hip/hip_runtime.h>
#include <math.h>

#define C 128
#define H 4
#define DH 32
#define LMAX 64
#define EPS 1e-5f
#define ISQ 0.17677669529663687f   // 1/sqrt(32)

__device__ __forceinline__ float wsum(float v){
  #pragma unroll
  for (int o = 32; o > 0; o >>= 1) v += __shfl_xor(v, o, 64);
  return v;
}
__device__ __forceinline__ float wmax(float v){
  #pragma unroll
  for (int o = 32; o > 0; o >>= 1) v = fmaxf(v, __shfl_xor(v, o, 64));
  return v;
}

// segment bounds from the sorted gene_idx: starts[g] = lower_bound(g), counts[g] = ub-lb
__global__ void seg_bounds_kernel(const int* __restrict__ gene_idx, int E, int G,
                                  int* __restrict__ starts, int* __restrict__ counts){
  int g = blockIdx.x * blockDim.x + threadIdx.x;
  if (g >= G) return;
  int lo = 0, hi = E;
  while (lo < hi){ int m = (lo + hi) >> 1; if (gene_idx[m] < g) lo = m + 1; else hi = m; }
  int s = lo;
  hi = E;
  while (lo < hi){ int m = (lo + hi) >> 1; if (gene_idx[m] < g + 1) lo = m + 1; else hi = m; }
  starts[g] = s; counts[g] = lo - s;
}

__global__ __launch_bounds__(256)
void gene_fused_kernel(const float* __restrict__ RF,
  const float* __restrict__ Wq, const float* __restrict__ Wk,
  const float* __restrict__ Wv, const float* __restrict__ Wo,
  const float* __restrict__ bq, const float* __restrict__ bk,
  const float* __restrict__ bv, const float* __restrict__ bo,
  const float* __restrict__ Wlin, const float* __restrict__ blin,
  const float* __restrict__ g1, const float* __restrict__ b1,
  const float* __restrict__ g2, const float* __restrict__ b2,
  const float* __restrict__ seed, const int* __restrict__ rxn_idx,
  const int* __restrict__ starts, const int* __restrict__ counts,
  float* __restrict__ out)
{
  __shared__ float xb[LMAX][C];     // activations
  __shared__ float ob[LMAX][C];     // second buffer
  __shared__ float qh[LMAX][DH];
  __shared__ float kh[LMAX][DH];
  __shared__ float vh[LMAX][DH];
  __shared__ float sc[LMAX][LMAX];  // per-head scores
  __shared__ float row0[C], row1[C], row2[C];

  const int g = blockIdx.x;
  const int t = threadIdx.x;
  const int lane = t & 63;
  const int wave = t >> 6;
  int L = counts[g]; if (L > LMAX) L = LMAX;   // to_dense_batch drops pos>=Lmax
  const int s0 = starts[g];

  // stage the L valid rows: xb[l][:] = RF[rxn_idx[s0+l]][:]
  for (int idx = t; idx < L * 32; idx += 256){
    int l = idx >> 5, c4 = idx & 31;
    int r = rxn_idx[s0 + l];
    *(float4*)(&xb[l][c4 * 4]) = *(const float4*)(RF + (size_t)r * C + c4 * 4);
  }
  __syncthreads();

  const int d  = t & 31,  lg  = t >> 5;   // DH-wide phases: 8 rows/thread, stride 8
  const int j  = t & 127, lg2 = t >> 7;   // C-wide phases: row chunks of 16

  // ---------------- encoder SABs (blk 0,1) ----------------
  for (int blk = 0; blk < 2; ++blk){
    const float* wq = Wq + blk * C * C; const float* wk = Wk + blk * C * C;
    const float* wv = Wv + blk * C * C; const float* wo = Wo + blk * C * C;
    const float* wl = Wlin + blk * C * C;

    for (int h = 0; h < H; ++h){
      // Q,K,V for this head
      float aq[8], ak[8], av[8];
      float bqv = bq[blk*C + h*DH + d], bkv = bk[blk*C + h*DH + d], bvv = bv[blk*C + h*DH + d];
      #pragma unroll
      for (int r8 = 0; r8 < 8; r8++){ aq[r8] = bqv; ak[r8] = bkv; av[r8] = bvv; }
      #pragma unroll 4
      for (int k = 0; k < C; k++){
        float wqv = wq[k*C + h*DH + d], wkv = wk[k*C + h*DH + d], wvv = wv[k*C + h*DH + d];
        #pragma unroll
        for (int r8 = 0; r8 < 8; r8++){
          float x = xb[lg + 8*r8][k];
          aq[r8] = fmaf(x, wqv, aq[r8]);
          ak[r8] = fmaf(x, wkv, ak[r8]);
          av[r8] = fmaf(x, wvv, av[r8]);
        }
      }
      #pragma unroll
      for (int r8 = 0; r8 < 8; r8++){
        int l = lg + 8*r8;
        if (l < L){ qh[l][d] = aq[r8]; kh[l][d] = ak[r8]; vh[l][d] = av[r8]; }
      }
      __syncthreads();

      // scores
      for (int idx = t; idx < L * L; idx += 256){
        int q = idx / L, k = idx - q * L;
        float acc = 0.f;
        #pragma unroll
        for (int dd = 0; dd < DH; dd++) acc = fmaf(qh[q][dd], kh[k][dd], acc);
        sc[q][k] = acc * ISQ;
      }
      __syncthreads();

      // softmax per row (one wave per row)
      for (int q = wave; q < L; q += 4){
        float v = (lane < L) ? sc[q][lane] : -INFINITY;
        float m = wmax(v);
        float e = (lane < L) ? __expf(v - m) : 0.f;
        float s = wsum(e);
        if (lane < L) sc[q][lane] = e / s;
      }
      __syncthreads();

      // attn @ V -> ob column block of this head
      float ao[8];
      #pragma unroll
      for (int r8 = 0; r8 < 8; r8++) ao[r8] = 0.f;
      for (int k = 0; k < L; k++){
        float vv = vh[k][d];
        #pragma unroll
        for (int r8 = 0; r8 < 8; r8++) ao[r8] = fmaf(sc[lg + 8*r8][k], vv, ao[r8]);
      }
      #pragma unroll
      for (int r8 = 0; r8 < 8; r8++){ int l = lg + 8*r8; if (l < L) ob[l][h*DH + d] = ao[r8]; }
      __syncthreads();
    }

    // attn_concat @ Wo + bo + residual -> xb (each element read+written by one thread)
    for (int l0 = 0; l0 < L; l0 += 16){
      float acc[8]; float bb = bo[blk*C + j];
      #pragma unroll
      for (int r8 = 0; r8 < 8; r8++) acc[r8] = bb;
      #pragma unroll 4
      for (int k = 0; k < C; k++){
        float w = wo[k*C + j];
        #pragma unroll
        for (int r8 = 0; r8 < 8; r8++) acc[r8] = fmaf(ob[l0 + lg2*8 + r8][k], w, acc[r8]);
      }
      #pragma unroll
      for (int r8 = 0; r8 < 8; r8++){
        int l = l0 + lg2*8 + r8;
        if (l < L) xb[l][j] += acc[r8];
      }
    }
    __syncthreads();

    // LN1 in place on xb
    for (int l = wave; l < L; l += 4){
      float v0 = xb[l][lane], v1 = xb[l][lane + 64];
      float m = wsum(v0 + v1) * (1.f / C);
      float d0 = v0 - m, d1 = v1 - m;
      float va = wsum(d0*d0 + d1*d1) * (1.f / C);
      float rs = rsqrtf(va + EPS);
      xb[l][lane]      = d0 * rs * g1[blk*C + lane]      + b1[blk*C + lane];
      xb[l][lane + 64] = d1 * rs * g1[blk*C + lane + 64] + b1[blk*C + lane + 64];
    }
    __syncthreads();

    // FF: ob = xb + relu(xb @ Wlin + blin)
    for (int l0 = 0; l0 < L; l0 += 16){
      float acc[8]; float bb = blin[blk*C + j];
      #pragma unroll
      for (int r8 = 0; r8 < 8; r8++) acc[r8] = bb;
      #pragma unroll 4
      for (int k = 0; k < C; k++){
        float w = wl[k*C + j];
        #pragma unroll
        for (int r8 = 0; r8 < 8; r8++) acc[r8] = fmaf(xb[l0 + lg2*8 + r8][k], w, acc[r8]);
      }
      #pragma unroll
      for (int r8 = 0; r8 < 8; r8++){
        int l = l0 + lg2*8 + r8;
        if (l < L) ob[l][j] = xb[l][j] + fmaxf(acc[r8], 0.f);
      }
    }
    __syncthreads();

    // LN2: ob -> xb (block output)
    for (int l = wave; l < L; l += 4){
      float v0 = ob[l][lane], v1 = ob[l][lane + 64];
      float m = wsum(v0 + v1) * (1.f / C);
      float d0 = v0 - m, d1 = v1 - m;
      float va = wsum(d0*d0 + d1*d1) * (1.f / C);
      float rs = rsqrtf(va + EPS);
      xb[l][lane]      = d0 * rs * g2[blk*C + lane]      + b2[blk*C + lane];
      xb[l][lane + 64] = d1 * rs * g2[blk*C + lane + 64] + b2[blk*C + lane + 64];
    }
    __syncthreads();
  }

  // ---------------- PMA (blk 2): 1 seed query ----------------
  {
    const float* wq2 = Wq + 2*C*C; const float* wk2 = Wk + 2*C*C;
    const float* wv2 = Wv + 2*C*C; const float* wo2 = Wo + 2*C*C;
    const float* wl2 = Wlin + 2*C*C;

    // q row = seed @ Wq2 + bq2 -> row0
    if (t < C){
      float acc = bq[2*C + t];
      #pragma unroll 4
      for (int k = 0; k < C; k++) acc = fmaf(seed[k], wq2[k*C + t], acc);
      row0[t] = acc;
    }
    __syncthreads();

    for (int h = 0; h < H; ++h){
      float ak[8], av[8];
      float bkv = bk[2*C + h*DH + d], bvv = bv[2*C + h*DH + d];
      #pragma unroll
      for (int r8 = 0; r8 < 8; r8++){ ak[r8] = bkv; av[r8] = bvv; }
      #pragma unroll 4
      for (int k = 0; k < C; k++){
        float wkv = wk2[k*C + h*DH + d], wvv = wv2[k*C + h*DH + d];
        #pragma unroll
        for (int r8 = 0; r8 < 8; r8++){
          float x = xb[lg + 8*r8][k];
          ak[r8] = fmaf(x, wkv, ak[r8]); av[r8] = fmaf(x, wvv, av[r8]);
        }
      }
      #pragma unroll
      for (int r8 = 0; r8 < 8; r8++){ int l = lg + 8*r8; if (l < L){ kh[l][d] = ak[r8]; vh[l][d] = av[r8]; } }
      __syncthreads();

      if (wave == 0){
        float v = -INFINITY;
        if (lane < L){
          float acc = 0.f;
          #pragma unroll
          for (int dd = 0; dd < DH; dd++) acc = fmaf(row0[h*DH + dd], kh[lane][dd], acc);
          v = acc * ISQ;
        }
        float m = wmax(v);
        float e = (lane < L) ? __expf(v - m) : 0.f;
        float s = wsum(e);
        sc[0][lane] = (lane < L) ? e / s : 0.f;
      }
      __syncthreads();
      if (t < DH){
        float acc = 0.f;
        for (int k = 0; k < L; k++) acc = fmaf(sc[0][k], vh[k][t], acc);
        row1[h*DH + t] = acc;
      }
      __syncthreads();
    }

    // y = attn @ Wo2 + bo2 + seed -> row0
    if (t < C){
      float acc = bo[2*C + t];
      #pragma unroll 4
      for (int k = 0; k < C; k++) acc = fmaf(row1[k], wo2[k*C + t], acc);
      row0[t] = acc + seed[t];
    }
    __syncthreads();
    if (wave == 0){ // LN1
      float v0 = row0[lane], v1 = row0[lane + 64];
      float m = wsum(v0 + v1) * (1.f / C);
      float d0 = v0 - m, d1 = v1 - m;
      float va = wsum(d0*d0 + d1*d1) * (1.f / C);
      float rs = rsqrtf(va + EPS);
      row0[lane]      = d0 * rs * g1[2*C + lane]      + b1[2*C + lane];
      row0[lane + 64] = d1 * rs * g1[2*C + lane + 64] + b1[2*C + lane + 64];
    }
    __syncthreads();
    if (t < C){ // FF -> row1
      float acc = blin[2*C + t];
      #pragma unroll 4
      for (int k = 0; k < C; k++) acc = fmaf(row0[k], wl2[k*C + t], acc);
      row1[t] = row0[t] + fmaxf(acc, 0.f);
    }
    __syncthreads();
    if (wave == 0){ // LN2 -> row0 = h3
      float v0 = row1[lane], v1 = row1[lane + 64];
      float m = wsum(v0 + v1) * (1.f / C);
      float d0 = v0 - m, d1 = v1 - m;
      float va = wsum(d0*d0 + d1*d1) * (1.f / C);
      float rs = rsqrtf(va + EPS);
      row0[lane]      = d0 * rs * g2[2*C + lane]      + b2[2*C + lane];
      row0[lane + 64] = d1 * rs * g2[2*C + lane + 64] + b2[2*C + lane + 64];
    }
    __syncthreads();
  }

  // ---------------- decoder SAB (blk 3): Lq=Lk=1, softmax(1)=1 ----------------
  {
    const float* wv3 = Wv + 3*C*C; const float* wo3 = Wo + 3*C*C; const float* wl3 = Wlin + 3*C*C;
    if (t < C){ // v = h3 @ Wv3 + bv3 -> row1
      float acc = bv[3*C + t];
      #pragma unroll 4
      for (int k = 0; k < C; k++) acc = fmaf(row0[k], wv3[k*C + t], acc);
      row1[t] = acc;
    }
    __syncthreads();
    if (t < C){ // y = v @ Wo3 + bo3 + h3 -> row2
      float acc = bo[3*C + t];
      #pragma unroll 4
      for (int k = 0; k < C; k++) acc = fmaf(row1[k], wo3[k*C + t], acc);
      row2[t] = acc + row0[t];
    }
    __syncthreads();
    if (wave == 0){ // LN1 in place
      float v0 = row2[lane], v1 = row2[lane + 64];
      float m = wsum(v0 + v1) * (1.f / C);
      float d0 = v0 - m, d1 = v1 - m;
      float va = wsum(d0*d0 + d1*d1) * (1.f / C);
      float rs = rsqrtf(va + EPS);
      row2[lane]      = d0 * rs * g1[3*C + lane]      + b1[3*C + lane];
      row2[lane + 64] = d1 * rs * g1[3*C + lane + 64] + b1[3*C + lane + 64];
    }
    __syncthreads();
    if (t < C){ // FF -> row1
      float acc = blin[3*C + t];
      #pragma unroll 4
      for (int k = 0; k < C; k++) acc = fmaf(row2[k], wl3[k*C + t], acc);
      row1[t] = row2[t] + fmaxf(acc, 0.f);
    }
    __syncthreads();
    if (wave == 0){ // LN2 + nan_to_num + store
      float v0 = row1[lane], v1 = row1[lane + 64];
      float m = wsum(v0 + v1) * (1.f / C);
      float d0 = v0 - m, d1 = v1 - m;
      float va = wsum(d0*d0 + d1*d1) * (1.f / C);
      float rs = rsqrtf(va + EPS);
      float r0 = d0 * rs * g2[3*C + lane]      + b2[3*C + lane];
      float r1 = d1 * rs * g2[3*C + lane + 64] + b2[3*C + lane + 64];
      if (isnan(r0)) r0 = 0.f; else if (isinf(r0)) r0 = r0 > 0 ? 3.402823466e38f : -3.402823466e38f;
      if (isnan(r1)) r1 = 0.f; else if (isinf(r1)) r1 = r1 > 0 ? 3.402823466e38f : -3.402823466e38f;
      out[(size_t)g*C + lane]      = r0;
      out[(size_t)g*C + lane + 64] = r1;
    }
  }
}

extern "C" void kernel_launch(void* const* d_in, const int* in_sizes, int n_in,
                              void* d_out, int out_size, void* d_ws, size_t ws_size,
                              hipStream_t stream){
  const float* RF   = (const float*)d_in[0];
  const float* Wq   = (const float*)d_in[1];
  const float* Wk   = (const float*)d_in[2];
  const float* Wv   = (const float*)d_in[3];
  const float* Wo   = (const float*)d_in[4];
  const float* bq   = (const float*)d_in[5];
  const float* bk   = (const float*)d_in[6];
  const float* bv   = (const float*)d_in[7];
  const float* bo   = (const float*)d_in[8];
  const float* Wlin = (const float*)d_in[9];
  const float* blin = (const float*)d_in[10];
  const float* g1   = (const float*)d_in[11];
  const float* b1   = (const float*)d_in[12];
  const float* g2   = (const float*)d_in[13];
  const float* b2   = (const float*)d_in[14];
  const float* seed = (const float*)d_in[15];
  const int* rxn    = (const int*)d_in[16];
  const int* gidx   = (const int*)d_in[17];

  int E = in_sizes[16];
  int G = out_size / C;

  int* starts = (int*)d_ws;
  int* counts = starts + G;

  seg_bounds_kernel<<<(G + 255) / 256, 256, 0, stream>>>(gidx, E, G, starts, counts);
  gene_fused_kernel<<<G, 256, 0, stream>>>(RF, Wq, Wk, Wv, Wo, bq, bk, bv, bo,
      Wlin, blin, g1, b1, g2, b2, seed, rxn, starts, counts, (float*)d_out);
}

// Round 2
// 1721.577 us; speedup vs baseline: 1.9867x; 1.9867x over previous
//
#include <hip/hip_runtime.h>
#include <hip/hip_bf16.h>
#include <math.h>

#define C 128
#define H 4
#define DH 32
#define DHP 33
#define LMAX 64
#define EPS 1e-5f
#define ISQ 0.17677669529663687f   // 1/sqrt(32)

__device__ __forceinline__ float wsum(float v){
  #pragma unroll
  for (int o = 32; o > 0; o >>= 1) v += __shfl_xor(v, o, 64);
  return v;
}
__device__ __forceinline__ float wmax(float v){
  #pragma unroll
  for (int o = 32; o > 0; o >>= 1) v = fmaxf(v, __shfl_xor(v, o, 64));
  return v;
}
__device__ __forceinline__ unsigned short f2b(float f){
  __hip_bfloat16 b = __float2bfloat16(f);   // RNE
  union { __hip_bfloat16 b; unsigned short u; } cv; cv.b = b; return cv.u;
}
__device__ __forceinline__ float b2f(unsigned short u){
  return __uint_as_float(((unsigned)u) << 16);
}

// segment bounds from the sorted gene_idx
__global__ void seg_bounds_kernel(const int* __restrict__ gene_idx, int E, int G,
                                  int* __restrict__ starts, int* __restrict__ counts){
  int g = blockIdx.x * blockDim.x + threadIdx.x;
  if (g >= G) return;
  int lo = 0, hi = E;
  while (lo < hi){ int m = (lo + hi) >> 1; if (gene_idx[m] < g) lo = m + 1; else hi = m; }
  int s = lo;
  hi = E;
  while (lo < hi){ int m = (lo + hi) >> 1; if (gene_idx[m] < g + 1) lo = m + 1; else hi = m; }
  starts[g] = s; counts[g] = lo - s;
}

// ---- per-head encoder SAB body, NR8 = ceil(L/8) (compile-time) ----
template<int NR8>
__device__ __forceinline__ void enc_head(
    int t, int L, int h,
    const float* __restrict__ wq, const float* __restrict__ wk, const float* __restrict__ wv,
    float bqv, float bkv, float bvv,
    const unsigned short (*xb)[C], unsigned short (*ob)[C],
    float (*qh)[DHP], float (*kh)[DHP], float (*vh)[DHP], float (*sc)[LMAX])
{
  const int lane = t & 63, wave = t >> 6;
  const int d = t & 31, lg = t >> 5;     // lg in 0..7 -> rows lg + 8*r
  float aq[NR8], ak[NR8], av[NR8];
  #pragma unroll
  for (int r = 0; r < NR8; r++){ aq[r] = bqv; ak[r] = bkv; av[r] = bvv; }
  #pragma unroll 4
  for (int k = 0; k < C; k++){
    float wqv = wq[k*C + h*DH + d], wkv = wk[k*C + h*DH + d], wvv = wv[k*C + h*DH + d];
    #pragma unroll
    for (int r = 0; r < NR8; r++){
      float x = b2f(xb[lg + 8*r][k]);
      aq[r] = fmaf(x, wqv, aq[r]);
      ak[r] = fmaf(x, wkv, ak[r]);
      av[r] = fmaf(x, wvv, av[r]);
    }
  }
  #pragma unroll
  for (int r = 0; r < NR8; r++){
    int l = lg + 8*r;
    if (l < L){ qh[l][d] = aq[r]; kh[l][d] = ak[r]; vh[l][d] = av[r]; }
  }
  __syncthreads();

  // scores (padded qh/kh -> conflict-free)
  for (int idx = t; idx < L * L; idx += 256){
    int q = idx / L, k = idx - q * L;
    float acc = 0.f;
    #pragma unroll
    for (int dd = 0; dd < DH; dd++) acc = fmaf(qh[q][dd], kh[k][dd], acc);
    sc[q][k] = acc * ISQ;
  }
  __syncthreads();

  // softmax per row (one wave per row)
  for (int q = wave; q < L; q += 4){
    float v = (lane < L) ? sc[q][lane] : -INFINITY;
    float m = wmax(v);
    float e = (lane < L) ? __expf(v - m) : 0.f;
    float s = wsum(e);
    if (lane < L) sc[q][lane] = e / s;
  }
  __syncthreads();

  // attn @ V -> ob column block of this head
  float ao[NR8];
  #pragma unroll
  for (int r = 0; r < NR8; r++) ao[r] = 0.f;
  for (int k = 0; k < L; k++){
    float vv = vh[k][d];
    #pragma unroll
    for (int r = 0; r < NR8; r++) ao[r] = fmaf(sc[lg + 8*r][k], vv, ao[r]);
  }
  #pragma unroll
  for (int r = 0; r < NR8; r++){ int l = lg + 8*r; if (l < L) ob[l][h*DH + d] = f2b(ao[r]); }
  __syncthreads();
}

// ---- per-head PMA body (K/V projection + 1-query attention) ----
template<int NR8>
__device__ __forceinline__ void pma_head(
    int t, int L, int h,
    const float* __restrict__ wk2, const float* __restrict__ wv2,
    float bkv, float bvv,
    const unsigned short (*xb)[C],
    float (*kh)[DHP], float (*vh)[DHP], float* sc0,
    const float* qrow, float* row1)
{
  const int lane = t & 63, wave = t >> 6;
  const int d = t & 31, lg = t >> 5;
  float ak[NR8], av[NR8];
  #pragma unroll
  for (int r = 0; r < NR8; r++){ ak[r] = bkv; av[r] = bvv; }
  #pragma unroll 4
  for (int k = 0; k < C; k++){
    float wkv = wk2[k*C + h*DH + d], wvv = wv2[k*C + h*DH + d];
    #pragma unroll
    for (int r = 0; r < NR8; r++){
      float x = b2f(xb[lg + 8*r][k]);
      ak[r] = fmaf(x, wkv, ak[r]); av[r] = fmaf(x, wvv, av[r]);
    }
  }
  #pragma unroll
  for (int r = 0; r < NR8; r++){ int l = lg + 8*r; if (l < L){ kh[l][d] = ak[r]; vh[l][d] = av[r]; } }
  __syncthreads();

  if (wave == 0){
    float v = -INFINITY;
    if (lane < L){
      float acc = 0.f;
      #pragma unroll
      for (int dd = 0; dd < DH; dd++) acc = fmaf(qrow[h*DH + dd], kh[lane][dd], acc);
      v = acc * ISQ;
    }
    float m = wmax(v);
    float e = (lane < L) ? __expf(v - m) : 0.f;
    float s = wsum(e);
    sc0[lane] = (lane < L) ? e / s : 0.f;
  }
  __syncthreads();
  if (t < DH){
    float acc = 0.f;
    for (int k = 0; k < L; k++) acc = fmaf(sc0[k], vh[k][t], acc);
    row1[h*DH + t] = acc;
  }
  __syncthreads();
}

__global__ __launch_bounds__(256)
void gene_fused_kernel(const float* __restrict__ RF,
  const float* __restrict__ Wq, const float* __restrict__ Wk,
  const float* __restrict__ Wv, const float* __restrict__ Wo,
  const float* __restrict__ bq, const float* __restrict__ bk,
  const float* __restrict__ bv, const float* __restrict__ bo,
  const float* __restrict__ Wlin, const float* __restrict__ blin,
  const float* __restrict__ g1, const float* __restrict__ b1,
  const float* __restrict__ g2, const float* __restrict__ b2,
  const float* __restrict__ seed, const int* __restrict__ rxn_idx,
  const int* __restrict__ starts, const int* __restrict__ counts,
  float* __restrict__ out)
{
  __shared__ unsigned short xb[LMAX][C];   // activations (bf16) 16KB
  __shared__ unsigned short ob[LMAX][C];   // second buffer (bf16) 16KB
  __shared__ float qh[LMAX][DHP];          // 8.25KB (padded)
  __shared__ float kh[LMAX][DHP];
  __shared__ float vh[LMAX][DHP];
  __shared__ float sc[LMAX][LMAX];         // 16KB
  __shared__ float row0[C], row1[C], row2[C];

  const int g = blockIdx.x;
  const int t = threadIdx.x;
  const int lane = t & 63;
  const int wave = t >> 6;
  int L = counts[g]; if (L > LMAX) L = LMAX;
  const int s0 = starts[g];
  const int nr8 = (L <= 8) ? 1 : (L <= 16) ? 2 : (L <= 32) ? 4 : 8;

  // stage valid rows as bf16
  for (int idx = t; idx < L * 32; idx += 256){
    int l = idx >> 5, c4 = idx & 31;
    int r = rxn_idx[s0 + l];
    float4 v = *(const float4*)(RF + (size_t)r * C + c4 * 4);
    ushort4 u; u.x = f2b(v.x); u.y = f2b(v.y); u.z = f2b(v.z); u.w = f2b(v.w);
    *(ushort4*)(&xb[l][c4 * 4]) = u;
  }
  __syncthreads();

  const int d = t & 31;
  const int j = t & 127, lg2 = t >> 7;

  // ---------------- encoder SABs (blk 0,1) ----------------
  for (int blk = 0; blk < 2; ++blk){
    const float* wq = Wq + blk * C * C; const float* wk = Wk + blk * C * C;
    const float* wv = Wv + blk * C * C; const float* wo = Wo + blk * C * C;
    const float* wl = Wlin + blk * C * C;

    switch (nr8){
      case 1: for (int h = 0; h < H; ++h) enc_head<1>(t, L, h, wq, wk, wv,
                 bq[blk*C + h*DH + d], bk[blk*C + h*DH + d], bv[blk*C + h*DH + d],
                 xb, ob, qh, kh, vh, sc); break;
      case 2: for (int h = 0; h < H; ++h) enc_head<2>(t, L, h, wq, wk, wv,
                 bq[blk*C + h*DH + d], bk[blk*C + h*DH + d], bv[blk*C + h*DH + d],
                 xb, ob, qh, kh, vh, sc); break;
      case 4: for (int h = 0; h < H; ++h) enc_head<4>(t, L, h, wq, wk, wv,
                 bq[blk*C + h*DH + d], bk[blk*C + h*DH + d], bv[blk*C + h*DH + d],
                 xb, ob, qh, kh, vh, sc); break;
      default: for (int h = 0; h < H; ++h) enc_head<8>(t, L, h, wq, wk, wv,
                 bq[blk*C + h*DH + d], bk[blk*C + h*DH + d], bv[blk*C + h*DH + d],
                 xb, ob, qh, kh, vh, sc); break;
    }

    // attn_concat @ Wo + bo + residual -> xb
    for (int l0 = 0; l0 < L; l0 += 16){
      float acc[8]; float bb = bo[blk*C + j];
      #pragma unroll
      for (int r8 = 0; r8 < 8; r8++) acc[r8] = bb;
      #pragma unroll 4
      for (int k = 0; k < C; k++){
        float w = wo[k*C + j];
        #pragma unroll
        for (int r8 = 0; r8 < 8; r8++) acc[r8] = fmaf(b2f(ob[l0 + lg2*8 + r8][k]), w, acc[r8]);
      }
      #pragma unroll
      for (int r8 = 0; r8 < 8; r8++){
        int l = l0 + lg2*8 + r8;
        if (l < L) xb[l][j] = f2b(b2f(xb[l][j]) + acc[r8]);
      }
    }
    __syncthreads();

    // LN1 in place on xb
    for (int l = wave; l < L; l += 4){
      float v0 = b2f(xb[l][lane]), v1 = b2f(xb[l][lane + 64]);
      float m = wsum(v0 + v1) * (1.f / C);
      float d0 = v0 - m, d1 = v1 - m;
      float va = wsum(d0*d0 + d1*d1) * (1.f / C);
      float rs = rsqrtf(va + EPS);
      xb[l][lane]      = f2b(d0 * rs * g1[blk*C + lane]      + b1[blk*C + lane]);
      xb[l][lane + 64] = f2b(d1 * rs * g1[blk*C + lane + 64] + b1[blk*C + lane + 64]);
    }
    __syncthreads();

    // FF: ob = xb + relu(xb @ Wlin + blin)
    for (int l0 = 0; l0 < L; l0 += 16){
      float acc[8]; float bb = blin[blk*C + j];
      #pragma unroll
      for (int r8 = 0; r8 < 8; r8++) acc[r8] = bb;
      #pragma unroll 4
      for (int k = 0; k < C; k++){
        float w = wl[k*C + j];
        #pragma unroll
        for (int r8 = 0; r8 < 8; r8++) acc[r8] = fmaf(b2f(xb[l0 + lg2*8 + r8][k]), w, acc[r8]);
      }
      #pragma unroll
      for (int r8 = 0; r8 < 8; r8++){
        int l = l0 + lg2*8 + r8;
        if (l < L) ob[l][j] = f2b(b2f(xb[l][j]) + fmaxf(acc[r8], 0.f));
      }
    }
    __syncthreads();

    // LN2: ob -> xb
    for (int l = wave; l < L; l += 4){
      float v0 = b2f(ob[l][lane]), v1 = b2f(ob[l][lane + 64]);
      float m = wsum(v0 + v1) * (1.f / C);
      float d0 = v0 - m, d1 = v1 - m;
      float va = wsum(d0*d0 + d1*d1) * (1.f / C);
      float rs = rsqrtf(va + EPS);
      xb[l][lane]      = f2b(d0 * rs * g2[blk*C + lane]      + b2[blk*C + lane]);
      xb[l][lane + 64] = f2b(d1 * rs * g2[blk*C + lane + 64] + b2[blk*C + lane + 64]);
    }
    __syncthreads();
  }

  // ---------------- PMA (blk 2): 1 seed query ----------------
  {
    const float* wq2 = Wq + 2*C*C; const float* wk2 = Wk + 2*C*C;
    const float* wv2 = Wv + 2*C*C; const float* wo2 = Wo + 2*C*C;
    const float* wl2 = Wlin + 2*C*C;

    if (t < C){
      float acc = bq[2*C + t];
      #pragma unroll 4
      for (int k = 0; k < C; k++) acc = fmaf(seed[k], wq2[k*C + t], acc);
      row0[t] = acc;
    }
    __syncthreads();

    switch (nr8){
      case 1: for (int h = 0; h < H; ++h) pma_head<1>(t, L, h, wk2, wv2,
                 bk[2*C + h*DH + d], bv[2*C + h*DH + d], xb, kh, vh, &sc[0][0], row0, row1); break;
      case 2: for (int h = 0; h < H; ++h) pma_head<2>(t, L, h, wk2, wv2,
                 bk[2*C + h*DH + d], bv[2*C + h*DH + d], xb, kh, vh, &sc[0][0], row0, row1); break;
      case 4: for (int h = 0; h < H; ++h) pma_head<4>(t, L, h, wk2, wv2,
                 bk[2*C + h*DH + d], bv[2*C + h*DH + d], xb, kh, vh, &sc[0][0], row0, row1); break;
      default: for (int h = 0; h < H; ++h) pma_head<8>(t, L, h, wk2, wv2,
                 bk[2*C + h*DH + d], bv[2*C + h*DH + d], xb, kh, vh, &sc[0][0], row0, row1); break;
    }

    if (t < C){ // y = attn @ Wo2 + bo2 + seed -> row0
      float acc = bo[2*C + t];
      #pragma unroll 4
      for (int k = 0; k < C; k++) acc = fmaf(row1[k], wo2[k*C + t], acc);
      row0[t] = acc + seed[t];
    }
    __syncthreads();
    if (wave == 0){ // LN1
      float v0 = row0[lane], v1 = row0[lane + 64];
      float m = wsum(v0 + v1) * (1.f / C);
      float d0 = v0 - m, d1 = v1 - m;
      float va = wsum(d0*d0 + d1*d1) * (1.f / C);
      float rs = rsqrtf(va + EPS);
      row0[lane]      = d0 * rs * g1[2*C + lane]      + b1[2*C + lane];
      row0[lane + 64] = d1 * rs * g1[2*C + lane + 64] + b1[2*C + lane + 64];
    }
    __syncthreads();
    if (t < C){ // FF -> row1
      float acc = blin[2*C + t];
      #pragma unroll 4
      for (int k = 0; k < C; k++) acc = fmaf(row0[k], wl2[k*C + t], acc);
      row1[t] = row0[t] + fmaxf(acc, 0.f);
    }
    __syncthreads();
    if (wave == 0){ // LN2 -> row0 = h3
      float v0 = row1[lane], v1 = row1[lane + 64];
      float m = wsum(v0 + v1) * (1.f / C);
      float d0 = v0 - m, d1 = v1 - m;
      float va = wsum(d0*d0 + d1*d1) * (1.f / C);
      float rs = rsqrtf(va + EPS);
      row0[lane]      = d0 * rs * g2[2*C + lane]      + b2[2*C + lane];
      row0[lane + 64] = d1 * rs * g2[2*C + lane + 64] + b2[2*C + lane + 64];
    }
    __syncthreads();
  }

  // ---------------- decoder SAB (blk 3): Lq=Lk=1 ----------------
  {
    const float* wv3 = Wv + 3*C*C; const float* wo3 = Wo + 3*C*C; const float* wl3 = Wlin + 3*C*C;
    if (t < C){
      float acc = bv[3*C + t];
      #pragma unroll 4
      for (int k = 0; k < C; k++) acc = fmaf(row0[k], wv3[k*C + t], acc);
      row1[t] = acc;
    }
    __syncthreads();
    if (t < C){
      float acc = bo[3*C + t];
      #pragma unroll 4
      for (int k = 0; k < C; k++) acc = fmaf(row1[k], wo3[k*C + t], acc);
      row2[t] = acc + row0[t];
    }
    __syncthreads();
    if (wave == 0){
      float v0 = row2[lane], v1 = row2[lane + 64];
      float m = wsum(v0 + v1) * (1.f / C);
      float d0 = v0 - m, d1 = v1 - m;
      float va = wsum(d0*d0 + d1*d1) * (1.f / C);
      float rs = rsqrtf(va + EPS);
      row2[lane]      = d0 * rs * g1[3*C + lane]      + b1[3*C + lane];
      row2[lane + 64] = d1 * rs * g1[3*C + lane + 64] + b1[3*C + lane + 64];
    }
    __syncthreads();
    if (t < C){
      float acc = blin[3*C + t];
      #pragma unroll 4
      for (int k = 0; k < C; k++) acc = fmaf(row2[k], wl3[k*C + t], acc);
      row1[t] = row2[t] + fmaxf(acc, 0.f);
    }
    __syncthreads();
    if (wave == 0){
      float v0 = row1[lane], v1 = row1[lane + 64];
      float m = wsum(v0 + v1) * (1.f / C);
      float d0 = v0 - m, d1 = v1 - m;
      float va = wsum(d0*d0 + d1*d1) * (1.f / C);
      float rs = rsqrtf(va + EPS);
      float r0 = d0 * rs * g2[3*C + lane]      + b2[3*C + lane];
      float r1 = d1 * rs * g2[3*C + lane + 64] + b2[3*C + lane + 64];
      if (isnan(r0)) r0 = 0.f; else if (isinf(r0)) r0 = r0 > 0 ? 3.402823466e38f : -3.402823466e38f;
      if (isnan(r1)) r1 = 0.f; else if (isinf(r1)) r1 = r1 > 0 ? 3.402823466e38f : -3.402823466e38f;
      out[(size_t)g*C + lane]      = r0;
      out[(size_t)g*C + lane + 64] = r1;
    }
  }
}

extern "C" void kernel_launch(void* const* d_in, const int* in_sizes, int n_in,
                              void* d_out, int out_size, void* d_ws, size_t ws_size,
                              hipStream_t stream){
  const float* RF   = (const float*)d_in[0];
  const float* Wq   = (const float*)d_in[1];
  const float* Wk   = (const float*)d_in[2];
  const float* Wv   = (const float*)d_in[3];
  const float* Wo   = (const float*)d_in[4];
  const float* bq   = (const float*)d_in[5];
  const float* bk   = (const float*)d_in[6];
  const float* bv   = (const float*)d_in[7];
  const float* bo   = (const float*)d_in[8];
  const float* Wlin = (const float*)d_in[9];
  const float* blin = (const float*)d_in[10];
  const float* g1   = (const float*)d_in[11];
  const float* b1   = (const float*)d_in[12];
  const float* g2   = (const float*)d_in[13];
  const float* b2   = (const float*)d_in[14];
  const float* seed = (const float*)d_in[15];
  const int* rxn    = (const int*)d_in[16];
  const int* gidx   = (const int*)d_in[17];

  int E = in_sizes[16];
  int G = out_size / C;

  int* starts = (int*)d_ws;
  int* counts = starts + G;

  seg_bounds_kernel<<<(G + 255) / 256, 256, 0, stream>>>(gidx, E, G, starts, counts);
  gene_fused_kernel<<<G, 256, 0, stream>>>(RF, Wq, Wk, Wv, Wo, bq, bk, bv, bo,
      Wlin, blin, g1, b1, g2, b2, seed, rxn, starts, counts, (float*)d_out);
}

// Round 3
// 589.950 us; speedup vs baseline: 5.7974x; 2.9182x over previous
//
#include <hip/hip_runtime.h>
#include <hip/hip_bf16.h>
#include <math.h>

#define C 128
#define H 4
#define LMAX 64
#define EPS 1e-5f
#define ISQ 0.17677669529663687f   // 1/sqrt(32)

using short8  = __attribute__((ext_vector_type(8))) short;
using short4v = __attribute__((ext_vector_type(4))) short;
using f32x4   = __attribute__((ext_vector_type(4))) float;

__device__ __forceinline__ float wsum(float v){
  #pragma unroll
  for (int o = 32; o > 0; o >>= 1) v += __shfl_xor(v, o, 64);
  return v;
}
__device__ __forceinline__ float wmax(float v){
  #pragma unroll
  for (int o = 32; o > 0; o >>= 1) v = fmaxf(v, __shfl_xor(v, o, 64));
  return v;
}
__device__ __forceinline__ short f2bs(float f){
  __hip_bfloat16 b = __float2bfloat16(f);   // RNE
  union { __hip_bfloat16 b; short u; } cv; cv.b = b; return cv.u;
}
__device__ __forceinline__ float b2f(short u){
  return __uint_as_float(((unsigned)(unsigned short)u) << 16);
}

// ---- weight fragments: B-operand layout for mfma_f32_16x16x32_bf16 ----
// frag element: lane l, j -> W[kt*32 + (l>>4)*8 + j][nt*16 + (l&15)]
// stored at wf[(mat*4+blk)*16384 + (nt*4+kt)*512 + l*8 + j]
__global__ void prep_wfrag(const float* __restrict__ Wq, const float* __restrict__ Wk,
                           const float* __restrict__ Wv, const float* __restrict__ Wo,
                           const float* __restrict__ Wlin, short* __restrict__ wf){
  int bid = blockIdx.x, l = threadIdx.x;
  int tile = bid & 31, mb = bid >> 5;       // mb = mat*4+blk, 0..19
  int mat = mb >> 2, blk = mb & 3;
  const float* W = (mat==0?Wq : mat==1?Wk : mat==2?Wv : mat==3?Wo : Wlin) + blk*C*C;
  int nt = tile >> 2, kt = tile & 3;
  int col = nt*16 + (l & 15);
  int k0  = kt*32 + ((l >> 4) << 3);
  short8 v;
  #pragma unroll
  for (int j = 0; j < 8; j++) v[j] = f2bs(W[(k0 + j)*C + col]);
  *(short8*)(wf + ((size_t)mb*32 + tile)*512 + (size_t)l*8) = v;
}

// ---- segment bounds + binning by NT class ----
__global__ void seg_bin_kernel(const int* __restrict__ gidx, int E, int G,
                               int* __restrict__ starts, int* __restrict__ counts,
                               int* __restrict__ cnt, int* __restrict__ lists){
  int g = blockIdx.x * blockDim.x + threadIdx.x;
  if (g >= G) return;
  int lo = 0, hi = E;
  while (lo < hi){ int m = (lo + hi) >> 1; if (gidx[m] < g) lo = m + 1; else hi = m; }
  int s = lo; hi = E;
  while (lo < hi){ int m = (lo + hi) >> 1; if (gidx[m] < g + 1) lo = m + 1; else hi = m; }
  starts[g] = s;
  int c_ = lo - s; counts[g] = c_;
  int L = c_ > LMAX ? LMAX : c_; if (L < 1) L = 1;
  int cl = (L - 1) >> 4; if (cl > 3) cl = 3;
  int p = atomicAdd(&cnt[cl], 1);
  lists[cl*G + p] = g;
}

__device__ __forceinline__ f32x4 mfma4(short8 a0, short8 a1, short8 a2, short8 a3,
                                       const short* __restrict__ wf, int nt, int l){
  f32x4 acc = {0.f, 0.f, 0.f, 0.f};
  acc = __builtin_amdgcn_mfma_f32_16x16x32_bf16(a0, *(const short8*)(wf + ((nt*4+0)*64 + l)*8), acc, 0,0,0);
  acc = __builtin_amdgcn_mfma_f32_16x16x32_bf16(a1, *(const short8*)(wf + ((nt*4+1)*64 + l)*8), acc, 0,0,0);
  acc = __builtin_amdgcn_mfma_f32_16x16x32_bf16(a2, *(const short8*)(wf + ((nt*4+2)*64 + l)*8), acc, 0,0,0);
  acc = __builtin_amdgcn_mfma_f32_16x16x32_bf16(a3, *(const short8*)(wf + ((nt*4+3)*64 + l)*8), acc, 0,0,0);
  return acc;
}

template<int NT>
__global__ __launch_bounds__(256, 4) void gene_mfma_kernel(
  const float* __restrict__ RF, const short* __restrict__ wfrag,
  const float* __restrict__ Wq, const float* __restrict__ Wv,
  const float* __restrict__ Wo, const float* __restrict__ Wlin,
  const float* __restrict__ bq, const float* __restrict__ bk,
  const float* __restrict__ bv, const float* __restrict__ bo,
  const float* __restrict__ blin,
  const float* __restrict__ g1, const float* __restrict__ b1,
  const float* __restrict__ g2, const float* __restrict__ b2,
  const float* __restrict__ seed, const int* __restrict__ rxn_idx,
  const int* __restrict__ starts, const int* __restrict__ counts,
  const int* __restrict__ cnt, const int* __restrict__ lists, int cls, int G,
  float* __restrict__ out)
{
  constexpr int LP   = 16*NT;
  constexpr int KTPV = (NT + 1) / 2;     // ceil(LP/32)
  constexpr int PVK  = 32 * KTPV;        // PV K-dim (padded keys)
  constexpr int PBC  = PVK + 8;          // P buffer cols (bf16)
  constexpr int VTC  = PVK + 8;          // vt cols

  __shared__ short xb[LP][136];
  __shared__ short qb[LP][136];
  __shared__ short kb[LP][136];
  __shared__ short ob[LP][136];
  __shared__ short vt[128][VTC];         // V transposed: vt[dh][key]
  __shared__ short pb[LP][PBC];          // P (probs) bf16
  __shared__ float sc[LP][LP+1];         // scores fp32 (one head at a time)
  __shared__ float row0[C], row1[C], row2[C];
  __shared__ float pma_p[H][64];

  int nb = cnt[cls];
  if ((int)blockIdx.x >= nb) return;
  const int g = lists[cls*G + blockIdx.x];
  const int t = threadIdx.x, w = t >> 6, l = t & 63;
  int L = counts[g]; if (L > LMAX) L = LMAX;
  const int s0 = starts[g];

  // ---- stage xb (bf16), zero pad rows; zero vt used cols; zero pb ----
  for (int idx = t; idx < LP*32; idx += 256){
    int r8 = idx >> 5, c4 = idx & 31;
    short4v u = {0,0,0,0};
    if (r8 < L){
      int r = rxn_idx[s0 + r8];
      float4 v = *(const float4*)(RF + (size_t)r*C + c4*4);
      u[0]=f2bs(v.x); u[1]=f2bs(v.y); u[2]=f2bs(v.z); u[3]=f2bs(v.w);
    }
    *(short4v*)&xb[r8][c4*4] = u;
  }
  {
    short8 z = {0,0,0,0,0,0,0,0};
    for (int idx = t; idx < 128*(PVK/8); idx += 256){
      int row = idx / (PVK/8), ch = idx % (PVK/8);
      *(short8*)&vt[row][ch*8] = z;
    }
    for (int idx = t; idx < LP*(PBC/8); idx += 256){
      int row = idx / (PBC/8), ch = idx % (PBC/8);
      *(short8*)&pb[row][ch*8] = z;
    }
  }
  __syncthreads();

  // ================= encoder SABs (blk 0,1) =================
  for (int blk = 0; blk < 2; ++blk){
    const short* wfq = wfrag + (size_t)(0*4 + blk)*16384;
    const short* wfk = wfrag + (size_t)(1*4 + blk)*16384;
    const short* wfv = wfrag + (size_t)(2*4 + blk)*16384;
    const short* wfo = wfrag + (size_t)(3*4 + blk)*16384;
    const short* wfl = wfrag + (size_t)(4*4 + blk)*16384;

    // ---- phase A: QKV projections (MFMA) ----
    for (int mt = 0; mt < NT; ++mt){
      const short* p = &xb[mt*16 + (l&15)][(l>>4)<<3];
      short8 a0 = *(const short8*)(p);
      short8 a1 = *(const short8*)(p + 32);
      short8 a2 = *(const short8*)(p + 64);
      short8 a3 = *(const short8*)(p + 96);
      #pragma unroll
      for (int np = 0; np < 2; ++np){
        int nt = w*2 + np;
        int col = nt*16 + (l&15);
        f32x4 acc = mfma4(a0,a1,a2,a3, wfq, nt, l);
        float bb = bq[blk*C + col];
        #pragma unroll
        for (int r = 0; r < 4; r++) qb[mt*16 + (l>>4)*4 + r][col] = f2bs(acc[r] + bb);
        acc = mfma4(a0,a1,a2,a3, wfk, nt, l);
        bb = bk[blk*C + col];
        #pragma unroll
        for (int r = 0; r < 4; r++) kb[mt*16 + (l>>4)*4 + r][col] = f2bs(acc[r] + bb);
        acc = mfma4(a0,a1,a2,a3, wfv, nt, l);
        bb = bv[blk*C + col];
        short4v pk;
        #pragma unroll
        for (int r = 0; r < 4; r++) pk[r] = f2bs(acc[r] + bb);
        *(short4v*)&vt[col][mt*16 + (l>>4)*4] = pk;   // transposed
      }
    }
    __syncthreads();

    // ---- attention, heads serialized ----
    for (int h = 0; h < H; ++h){
      // scores: S = Q_h K_h^T (K=32, one MFMA per 16x16 tile)
      for (int idx = w; idx < NT*NT; idx += 4){
        int mt = idx / NT, nt = idx % NT;
        short8 a = *(const short8*)&qb[mt*16 + (l&15)][h*32 + ((l>>4)<<3)];
        short8 b = *(const short8*)&kb[nt*16 + (l&15)][h*32 + ((l>>4)<<3)];
        f32x4 acc = {0.f,0.f,0.f,0.f};
        acc = __builtin_amdgcn_mfma_f32_16x16x32_bf16(a, b, acc, 0,0,0);
        #pragma unroll
        for (int r = 0; r < 4; r++) sc[mt*16 + (l>>4)*4 + r][nt*16 + (l&15)] = acc[r]*ISQ;
      }
      __syncthreads();
      // softmax (masked) -> pb (bf16, padded cols already 0)
      for (int q = w; q < L; q += 4){
        float v = (l < L) ? sc[q][l] : -INFINITY;
        float m = wmax(v);
        float e = (l < L) ? __expf(v - m) : 0.f;
        float s = wsum(e);
        if (l < PVK) pb[q][l] = f2bs(e / s);
      }
      __syncthreads();
      // PV: O_h = P @ V_h  -> ob columns of this head
      for (int idx = w; idx < 2*NT; idx += 4){
        int mt = idx >> 1, nh = idx & 1;
        f32x4 acc = {0.f,0.f,0.f,0.f};
        #pragma unroll
        for (int kt = 0; kt < KTPV; kt++){
          short8 a = *(const short8*)&pb[mt*16 + (l&15)][kt*32 + ((l>>4)<<3)];
          short8 b = *(const short8*)&vt[h*32 + nh*16 + (l&15)][kt*32 + ((l>>4)<<3)];
          acc = __builtin_amdgcn_mfma_f32_16x16x32_bf16(a, b, acc, 0,0,0);
        }
        int col = h*32 + nh*16 + (l&15);
        #pragma unroll
        for (int r = 0; r < 4; r++) ob[mt*16 + (l>>4)*4 + r][col] = f2bs(acc[r]);
      }
      __syncthreads();
    }

    // ---- phase E: Wo + bo + residual -> xb ----
    for (int mt = 0; mt < NT; ++mt){
      const short* p = &ob[mt*16 + (l&15)][(l>>4)<<3];
      short8 a0 = *(const short8*)(p);
      short8 a1 = *(const short8*)(p + 32);
      short8 a2 = *(const short8*)(p + 64);
      short8 a3 = *(const short8*)(p + 96);
      #pragma unroll
      for (int np = 0; np < 2; ++np){
        int nt = w*2 + np;
        int col = nt*16 + (l&15);
        f32x4 acc = mfma4(a0,a1,a2,a3, wfo, nt, l);
        float bb = bo[blk*C + col];
        #pragma unroll
        for (int r = 0; r < 4; r++){
          int row = mt*16 + (l>>4)*4 + r;
          xb[row][col] = f2bs(acc[r] + bb + b2f(xb[row][col]));
        }
      }
    }
    __syncthreads();
    // LN1 (all LP rows keeps garbage bounded)
    for (int lr = w; lr < LP; lr += 4){
      float v0 = b2f(xb[lr][l]), v1 = b2f(xb[lr][l + 64]);
      float m = wsum(v0 + v1) * (1.f / C);
      float d0 = v0 - m, d1 = v1 - m;
      float va = wsum(d0*d0 + d1*d1) * (1.f / C);
      float rs = rsqrtf(va + EPS);
      xb[lr][l]      = f2bs(d0 * rs * g1[blk*C + l]      + b1[blk*C + l]);
      xb[lr][l + 64] = f2bs(d1 * rs * g1[blk*C + l + 64] + b1[blk*C + l + 64]);
    }
    __syncthreads();
    // ---- phase F: FF -> qb ----
    for (int mt = 0; mt < NT; ++mt){
      const short* p = &xb[mt*16 + (l&15)][(l>>4)<<3];
      short8 a0 = *(const short8*)(p);
      short8 a1 = *(const short8*)(p + 32);
      short8 a2 = *(const short8*)(p + 64);
      short8 a3 = *(const short8*)(p + 96);
      #pragma unroll
      for (int np = 0; np < 2; ++np){
        int nt = w*2 + np;
        int col = nt*16 + (l&15);
        f32x4 acc = mfma4(a0,a1,a2,a3, wfl, nt, l);
        float bb = blin[blk*C + col];
        #pragma unroll
        for (int r = 0; r < 4; r++){
          int row = mt*16 + (l>>4)*4 + r;
          float z = acc[r] + bb;
          qb[row][col] = f2bs(b2f(xb[row][col]) + fmaxf(z, 0.f));
        }
      }
    }
    __syncthreads();
    // LN2: qb -> xb
    for (int lr = w; lr < LP; lr += 4){
      float v0 = b2f(qb[lr][l]), v1 = b2f(qb[lr][l + 64]);
      float m = wsum(v0 + v1) * (1.f / C);
      float d0 = v0 - m, d1 = v1 - m;
      float va = wsum(d0*d0 + d1*d1) * (1.f / C);
      float rs = rsqrtf(va + EPS);
      xb[lr][l]      = f2bs(d0 * rs * g2[blk*C + l]      + b2[blk*C + l]);
      xb[lr][l + 64] = f2bs(d1 * rs * g2[blk*C + l + 64] + b2[blk*C + l + 64]);
    }
    __syncthreads();
  }

  // ================= PMA (blk 2) =================
  {
    const short* wfk = wfrag + (size_t)(1*4 + 2)*16384;
    const short* wfv = wfrag + (size_t)(2*4 + 2)*16384;
    // K,V projections (MFMA)
    for (int mt = 0; mt < NT; ++mt){
      const short* p = &xb[mt*16 + (l&15)][(l>>4)<<3];
      short8 a0 = *(const short8*)(p);
      short8 a1 = *(const short8*)(p + 32);
      short8 a2 = *(const short8*)(p + 64);
      short8 a3 = *(const short8*)(p + 96);
      #pragma unroll
      for (int np = 0; np < 2; ++np){
        int nt = w*2 + np;
        int col = nt*16 + (l&15);
        f32x4 acc = mfma4(a0,a1,a2,a3, wfk, nt, l);
        float bb = bk[2*C + col];
        #pragma unroll
        for (int r = 0; r < 4; r++) kb[mt*16 + (l>>4)*4 + r][col] = f2bs(acc[r] + bb);
        acc = mfma4(a0,a1,a2,a3, wfv, nt, l);
        bb = bv[2*C + col];
        short4v pk;
        #pragma unroll
        for (int r = 0; r < 4; r++) pk[r] = f2bs(acc[r] + bb);
        *(short4v*)&vt[col][mt*16 + (l>>4)*4] = pk;
      }
    }
    // q row = seed @ Wq2 + bq2
    if (t < C){
      float acc = bq[2*C + t];
      const float* wq2 = Wq + 2*C*C;
      #pragma unroll 4
      for (int k = 0; k < C; k++) acc = fmaf(seed[k], wq2[k*C + t], acc);
      row0[t] = acc;
    }
    __syncthreads();
    // heads in parallel: wave h owns head h
    {
      int h = w;
      float v = -INFINITY;
      if (l < L){
        float acc = 0.f;
        #pragma unroll 8
        for (int dd = 0; dd < 32; dd++) acc = fmaf(b2f(kb[l][h*32 + dd]), row0[h*32 + dd], acc);
        v = acc * ISQ;
      }
      float m = wmax(v);
      float e = (l < L) ? __expf(v - m) : 0.f;
      float s = wsum(e);
      pma_p[h][l] = e / s;
      if (l < 32){
        float acc = 0.f;
        for (int k = 0; k < L; k++) acc = fmaf(pma_p[h][k], b2f(vt[h*32 + l][k]), acc);
        row1[h*32 + l] = acc;
      }
    }
    __syncthreads();
    // y = attn @ Wo2 + bo2 + seed -> row0
    if (t < C){
      float acc = bo[2*C + t];
      const float* wo2 = Wo + 2*C*C;
      #pragma unroll 4
      for (int k = 0; k < C; k++) acc = fmaf(row1[k], wo2[k*C + t], acc);
      row0[t] = acc + seed[t];
    }
    __syncthreads();
    if (w == 0){ // LN1
      float v0 = row0[l], v1 = row0[l + 64];
      float m = wsum(v0 + v1) * (1.f / C);
      float d0 = v0 - m, d1 = v1 - m;
      float va = wsum(d0*d0 + d1*d1) * (1.f / C);
      float rs = rsqrtf(va + EPS);
      row0[l]      = d0 * rs * g1[2*C + l]      + b1[2*C + l];
      row0[l + 64] = d1 * rs * g1[2*C + l + 64] + b1[2*C + l + 64];
    }
    __syncthreads();
    if (t < C){ // FF -> row1
      float acc = blin[2*C + t];
      const float* wl2 = Wlin + 2*C*C;
      #pragma unroll 4
      for (int k = 0; k < C; k++) acc = fmaf(row0[k], wl2[k*C + t], acc);
      row1[t] = row0[t] + fmaxf(acc, 0.f);
    }
    __syncthreads();
    if (w == 0){ // LN2 -> row0 = h3
      float v0 = row1[l], v1 = row1[l + 64];
      float m = wsum(v0 + v1) * (1.f / C);
      float d0 = v0 - m, d1 = v1 - m;
      float va = wsum(d0*d0 + d1*d1) * (1.f / C);
      float rs = rsqrtf(va + EPS);
      row0[l]      = d0 * rs * g2[2*C + l]      + b2[2*C + l];
      row0[l + 64] = d1 * rs * g2[2*C + l + 64] + b2[2*C + l + 64];
    }
    __syncthreads();
  }

  // ================= decoder SAB (blk 3): Lq=Lk=1, softmax(1)=1 =================
  {
    const float* wv3 = Wv + 3*C*C; const float* wo3 = Wo + 3*C*C; const float* wl3 = Wlin + 3*C*C;
    if (t < C){
      float acc = bv[3*C + t];
      #pragma unroll 4
      for (int k = 0; k < C; k++) acc = fmaf(row0[k], wv3[k*C + t], acc);
      row1[t] = acc;
    }
    __syncthreads();
    if (t < C){
      float acc = bo[3*C + t];
      #pragma unroll 4
      for (int k = 0; k < C; k++) acc = fmaf(row1[k], wo3[k*C + t], acc);
      row2[t] = acc + row0[t];
    }
    __syncthreads();
    if (w == 0){
      float v0 = row2[l], v1 = row2[l + 64];
      float m = wsum(v0 + v1) * (1.f / C);
      float d0 = v0 - m, d1 = v1 - m;
      float va = wsum(d0*d0 + d1*d1) * (1.f / C);
      float rs = rsqrtf(va + EPS);
      row2[l]      = d0 * rs * g1[3*C + l]      + b1[3*C + l];
      row2[l + 64] = d1 * rs * g1[3*C + l + 64] + b1[3*C + l + 64];
    }
    __syncthreads();
    if (t < C){
      float acc = blin[3*C + t];
      #pragma unroll 4
      for (int k = 0; k < C; k++) acc = fmaf(row2[k], wl3[k*C + t], acc);
      row1[t] = row2[t] + fmaxf(acc, 0.f);
    }
    __syncthreads();
    if (w == 0){
      float v0 = row1[l], v1 = row1[l + 64];
      float m = wsum(v0 + v1) * (1.f / C);
      float d0 = v0 - m, d1 = v1 - m;
      float va = wsum(d0*d0 + d1*d1) * (1.f / C);
      float rs = rsqrtf(va + EPS);
      float r0 = d0 * rs * g2[3*C + l]      + b2[3*C + l];
      float r1 = d1 * rs * g2[3*C + l + 64] + b2[3*C + l + 64];
      if (isnan(r0)) r0 = 0.f; else if (isinf(r0)) r0 = r0 > 0 ? 3.402823466e38f : -3.402823466e38f;
      if (isnan(r1)) r1 = 0.f; else if (isinf(r1)) r1 = r1 > 0 ? 3.402823466e38f : -3.402823466e38f;
      out[(size_t)g*C + l]      = r0;
      out[(size_t)g*C + l + 64] = r1;
    }
  }
}

extern "C" void kernel_launch(void* const* d_in, const int* in_sizes, int n_in,
                              void* d_out, int out_size, void* d_ws, size_t ws_size,
                              hipStream_t stream){
  const float* RF   = (const float*)d_in[0];
  const float* Wq   = (const float*)d_in[1];
  const float* Wk   = (const float*)d_in[2];
  const float* Wv   = (const float*)d_in[3];
  const float* Wo   = (const float*)d_in[4];
  const float* bq   = (const float*)d_in[5];
  const float* bk   = (const float*)d_in[6];
  const float* bv   = (const float*)d_in[7];
  const float* bo   = (const float*)d_in[8];
  const float* Wlin = (const float*)d_in[9];
  const float* blin = (const float*)d_in[10];
  const float* g1   = (const float*)d_in[11];
  const float* b1   = (const float*)d_in[12];
  const float* g2   = (const float*)d_in[13];
  const float* b2   = (const float*)d_in[14];
  const float* seed = (const float*)d_in[15];
  const int* rxn    = (const int*)d_in[16];
  const int* gidx   = (const int*)d_in[17];

  int E = in_sizes[16];
  int G = out_size / C;

  // ws layout (bytes):
  //   0        .. 655360 : weight fragments (5 mats x 4 blks x 32KB, bf16)
  //   655360   .. 671744 : starts[G]
  //   671744   .. 688128 : counts[G]
  //   688128   .. 688144 : cnt[4]
  //   688144   .. +4G*4  : lists[4][G]
  short* wfrag = (short*)d_ws;
  int* starts = (int*)((char*)d_ws + 655360);
  int* counts = (int*)((char*)d_ws + 671744);
  int* cnt    = (int*)((char*)d_ws + 688128);
  int* lists  = (int*)((char*)d_ws + 688144);

  hipMemsetAsync(cnt, 0, 16, stream);
  prep_wfrag<<<640, 64, 0, stream>>>(Wq, Wk, Wv, Wo, Wlin, wfrag);
  seg_bin_kernel<<<(G + 255) / 256, 256, 0, stream>>>(gidx, E, G, starts, counts, cnt, lists);

  gene_mfma_kernel<1><<<G, 256, 0, stream>>>(RF, wfrag, Wq, Wv, Wo, Wlin,
      bq, bk, bv, bo, blin, g1, b1, g2, b2, seed, rxn, starts, counts,
      cnt, lists, 0, G, (float*)d_out);
  gene_mfma_kernel<2><<<G, 256, 0, stream>>>(RF, wfrag, Wq, Wv, Wo, Wlin,
      bq, bk, bv, bo, blin, g1, b1, g2, b2, seed, rxn, starts, counts,
      cnt, lists, 1, G, (float*)d_out);
  gene_mfma_kernel<3><<<G, 256, 0, stream>>>(RF, wfrag, Wq, Wv, Wo, Wlin,
      bq, bk, bv, bo, blin, g1, b1, g2, b2, seed, rxn, starts, counts,
      cnt, lists, 2, G, (float*)d_out);
  gene_mfma_kernel<4><<<G, 256, 0, stream>>>(RF, wfrag, Wq, Wv, Wo, Wlin,
      bq, bk, bv, bo, blin, g1, b1, g2, b2, seed, rxn, starts, counts,
      cnt, lists, 3, G, (float*)d_out);
}

// Round 4
// 310.145 us; speedup vs baseline: 11.0277x; 1.9022x over previous
//
#include <hip/hip_runtime.h>
#include <hip/hip_bf16.h>
#include <math.h>

#define C 128
#define H 4
#define LMAX 64
#define EPS 1e-5f
#define ISQ 0.17677669529663687f   // 1/sqrt(32)

using short8  = __attribute__((ext_vector_type(8))) short;
using short4v = __attribute__((ext_vector_type(4))) short;
using f32x4   = __attribute__((ext_vector_type(4))) float;

__device__ __forceinline__ float wsum(float v){
  #pragma unroll
  for (int o = 32; o > 0; o >>= 1) v += __shfl_xor(v, o, 64);
  return v;
}
__device__ __forceinline__ float wmax(float v){
  #pragma unroll
  for (int o = 32; o > 0; o >>= 1) v = fmaxf(v, __shfl_xor(v, o, 64));
  return v;
}
__device__ __forceinline__ short f2bs(float f){
  __hip_bfloat16 b = __float2bfloat16(f);   // RNE
  union { __hip_bfloat16 b; short u; } cv; cv.b = b; return cv.u;
}
__device__ __forceinline__ float b2f(short u){
  return __uint_as_float(((unsigned)(unsigned short)u) << 16);
}

// ---- weight fragments: B-operand layout for mfma_f32_16x16x32_bf16 ----
// lane l, j -> W[kt*32 + (l>>4)*8 + j][nt*16 + (l&15)]
__global__ void prep_wfrag(const float* __restrict__ Wq, const float* __restrict__ Wk,
                           const float* __restrict__ Wv, const float* __restrict__ Wo,
                           const float* __restrict__ Wlin, short* __restrict__ wf){
  int bid = blockIdx.x, l = threadIdx.x;
  int tile = bid & 31, mb = bid >> 5;       // mb = mat*4+blk, 0..19
  int mat = mb >> 2, blk = mb & 3;
  const float* W = (mat==0?Wq : mat==1?Wk : mat==2?Wv : mat==3?Wo : Wlin) + blk*C*C;
  int nt = tile >> 2, kt = tile & 3;
  int col = nt*16 + (l & 15);
  int k0  = kt*32 + ((l >> 4) << 3);
  short8 v;
  #pragma unroll
  for (int j = 0; j < 8; j++) v[j] = f2bs(W[(k0 + j)*C + col]);
  *(short8*)(wf + ((size_t)mb*32 + tile)*512 + (size_t)l*8) = v;
}

__global__ void prep_qrow(const float* __restrict__ seed, const float* __restrict__ Wq,
                          const float* __restrict__ bq, float* __restrict__ qrow){
  int t = threadIdx.x;
  const float* wq2 = Wq + 2*C*C;
  float acc = bq[2*C + t];
  #pragma unroll 4
  for (int k = 0; k < C; k++) acc = fmaf(seed[k], wq2[k*C + t], acc);
  qrow[t] = acc;
}

// ---- segment bounds + class ranks ----
__global__ void seg_kernel(const int* __restrict__ gidx, int E, int G,
                           int* __restrict__ starts, int* __restrict__ counts,
                           int* __restrict__ cnt, int* __restrict__ gcr){
  int g = blockIdx.x * blockDim.x + threadIdx.x;
  if (g >= G) return;
  int lo = 0, hi = E;
  while (lo < hi){ int m = (lo + hi) >> 1; if (gidx[m] < g) lo = m + 1; else hi = m; }
  int s = lo; hi = E;
  while (lo < hi){ int m = (lo + hi) >> 1; if (gidx[m] < g + 1) lo = m + 1; else hi = m; }
  starts[g] = s;
  int c_ = lo - s; counts[g] = c_;
  int L = c_ > LMAX ? LMAX : c_; if (L < 1) L = 1;
  int cl = (L - 1) >> 4;
  int r = atomicAdd(&cnt[cl], 1);
  gcr[g] = (cl << 28) | r;
}

// ---- bin assignment from class ranks (deterministic per gene output) ----
__global__ void fill_kernel(int G, const int* __restrict__ cnt, const int* __restrict__ gcr,
                            int* __restrict__ binfo, int* __restrict__ nbins){
  int g = blockIdx.x * blockDim.x + threadIdx.x;
  if (g >= G) return;
  int nb1 = (cnt[0] + 3) >> 2, nb2 = (cnt[1] + 1) >> 1, nb3 = cnt[2];
  if (g == 0) *nbins = nb1 + nb2 + nb3 + cnt[3];
  int v = gcr[g]; int cl = v >> 28; int r = v & 0x0FFFFFFF;
  int bin, slot;
  if      (cl == 0){ bin = r >> 2;             slot = r & 3; }
  else if (cl == 1){ bin = nb1 + (r >> 1);     slot = (r & 1) * 2; }
  else if (cl == 2){ bin = nb1 + nb2 + r;      slot = 0; }
  else             { bin = nb1 + nb2 + nb3 + r; slot = 0; }
  binfo[bin*4 + slot] = g;
}

__device__ __forceinline__ f32x4 mfma4(short8 a0, short8 a1, short8 a2, short8 a3,
                                       const short* __restrict__ wf, int nt, int l){
  f32x4 acc = {0.f, 0.f, 0.f, 0.f};
  acc = __builtin_amdgcn_mfma_f32_16x16x32_bf16(a0, *(const short8*)(wf + ((nt*4+0)*64 + l)*8), acc, 0,0,0);
  acc = __builtin_amdgcn_mfma_f32_16x16x32_bf16(a1, *(const short8*)(wf + ((nt*4+1)*64 + l)*8), acc, 0,0,0);
  acc = __builtin_amdgcn_mfma_f32_16x16x32_bf16(a2, *(const short8*)(wf + ((nt*4+2)*64 + l)*8), acc, 0,0,0);
  acc = __builtin_amdgcn_mfma_f32_16x16x32_bf16(a3, *(const short8*)(wf + ((nt*4+3)*64 + l)*8), acc, 0,0,0);
  return acc;
}

// LN over 64 rows x 128 cols: 4 threads per row, shfl_xor(1,2) group reduce
__device__ __forceinline__ void ln_rows(const short (*src)[136], short (*dst)[136],
                                        const float* __restrict__ gg,
                                        const float* __restrict__ bb, int t){
  int row = t >> 2, q4 = t & 3;
  float v[32];
  float sm = 0.f;
  #pragma unroll
  for (int kk = 0; kk < 32; ++kk){
    float x = b2f(src[row][q4*32 + kk]);
    v[kk] = x; sm += x;
  }
  sm += __shfl_xor(sm, 1);
  sm += __shfl_xor(sm, 2);
  float mean = sm * (1.f/128.f);
  float s2 = 0.f;
  #pragma unroll
  for (int kk = 0; kk < 32; ++kk){ float d = v[kk] - mean; s2 += d*d; }
  s2 += __shfl_xor(s2, 1);
  s2 += __shfl_xor(s2, 2);
  float rs = rsqrtf(s2*(1.f/128.f) + EPS);
  #pragma unroll
  for (int kk = 0; kk < 32; ++kk){
    int col = q4*32 + kk;
    dst[row][col] = f2bs((v[kk] - mean)*rs*gg[col] + bb[col]);
  }
}

__global__ __launch_bounds__(256, 2) void gene_bin_kernel(
  const float* __restrict__ RF, const short* __restrict__ wfrag,
  const float* __restrict__ qrow,
  const float* __restrict__ bq, const float* __restrict__ bk,
  const float* __restrict__ bv, const float* __restrict__ bo,
  const float* __restrict__ blin,
  const float* __restrict__ g1, const float* __restrict__ b1,
  const float* __restrict__ g2, const float* __restrict__ b2,
  const int* __restrict__ rxn_idx, const int* __restrict__ starts,
  const int* __restrict__ counts, const int* __restrict__ binfo,
  const int* __restrict__ meta, float* __restrict__ pooled)
{
  if ((int)blockIdx.x >= meta[0]) return;
  __shared__ short xb[64][136];            // activations (residual source)
  __shared__ short qb[64][136];            // Q, then attn-out (per-head overwrite)
  __shared__ short kb[64][136];            // K, then FF temp, then PMA K
  __shared__ short vt[128][72];            // V^T: vt[d][key]
  __shared__ __align__(16) short sc[64][72]; // logits -> probs (in-place); later aliased fp32 PMA probs
  __shared__ float qrl[C];
  __shared__ int mg[4], mL[4], ms0[4], mbase[4];

  const int bin = blockIdx.x;
  const int t = threadIdx.x, w = t >> 6, l = t & 63;
  const int hi = l >> 4, c = l & 15;

  if (t == 0){
    int s = 0;
    while (s < 4){
      int g = binfo[bin*4 + s];
      if (g >= 0){
        int Lg = counts[g]; if (Lg > LMAX) Lg = LMAX;
        int ntg = (Lg + 15) >> 4;
        for (int u = 0; u < ntg; ++u){ mg[s+u] = g; mL[s+u] = Lg; ms0[s+u] = starts[g]; mbase[s+u] = s; }
        s += ntg;
      } else { mg[s] = -1; mL[s] = 0; ms0[s] = 0; mbase[s] = s; s++; }
    }
  }
  if (t < C) qrl[t] = qrow[t];
  __syncthreads();

  // ---- stage rows (bf16), zero pads; zero sc once (cross-gene cols stay 0 forever) ----
  for (int idx = t; idx < 64*16; idx += 256){
    int row = idx >> 4, ch = idx & 15;
    int s = row >> 4;
    int g = mg[s];
    int ro = row - mbase[s]*16;
    short8 u = {0,0,0,0,0,0,0,0};
    if (g >= 0 && ro < mL[s]){
      int rr = rxn_idx[ms0[s] + ro];
      const float* src = RF + (size_t)rr*C + ch*8;
      float4 v0 = *(const float4*)(src);
      float4 v1 = *(const float4*)(src + 4);
      u[0]=f2bs(v0.x); u[1]=f2bs(v0.y); u[2]=f2bs(v0.z); u[3]=f2bs(v0.w);
      u[4]=f2bs(v1.x); u[5]=f2bs(v1.y); u[6]=f2bs(v1.z); u[7]=f2bs(v1.w);
    }
    *(short8*)&xb[row][ch*8] = u;
  }
  {
    short8 z = {0,0,0,0,0,0,0,0};
    for (int idx = t; idx < 64*9; idx += 256){
      int row = idx / 9, ch = idx - row*9;
      *(short8*)&sc[row][ch*8] = z;
    }
  }
  __syncthreads();

  // ================= encoder SABs (blk 0,1) =================
  for (int blk = 0; blk < 2; ++blk){
    // ---- QKV projections ----
    {
      short8 ax[4][4];
      #pragma unroll
      for (int mt = 0; mt < 4; ++mt)
        #pragma unroll
        for (int kk = 0; kk < 4; ++kk)
          ax[mt][kk] = *(const short8*)&xb[mt*16 + c][kk*32 + hi*8];
      #pragma unroll
      for (int i = 0; i < 6; ++i){
        int pr = w + 4*i;                 // 0..23 = (mat 0..2) x (nt 0..7)
        int mat = pr >> 3, nt = pr & 7;
        const short* wfm = wfrag + (size_t)(mat*4 + blk)*16384;
        const float* bias = (mat == 0 ? bq : mat == 1 ? bk : bv);
        int col = nt*16 + c;
        float bb = bias[blk*C + col];
        #pragma unroll
        for (int mt = 0; mt < 4; ++mt){
          f32x4 acc = mfma4(ax[mt][0], ax[mt][1], ax[mt][2], ax[mt][3], wfm, nt, l);
          if (mat == 2){
            short4v pk;
            #pragma unroll
            for (int r = 0; r < 4; r++) pk[r] = f2bs(acc[r] + bb);
            *(short4v*)&vt[col][mt*16 + hi*4] = pk;     // transposed
          } else if (mat == 0){
            #pragma unroll
            for (int r = 0; r < 4; r++) qb[mt*16 + hi*4 + r][col] = f2bs(acc[r] + bb);
          } else {
            #pragma unroll
            for (int r = 0; r < 4; r++) kb[mt*16 + hi*4 + r][col] = f2bs(acc[r] + bb);
          }
        }
      }
    }
    __syncthreads();

    // ---- attention (heads serialized; block-diagonal over genes) ----
    for (int h = 0; h < H; ++h){
      // scores (bf16 logits into sc, C-layout)
      for (int idx = w; idx < 16; idx += 4){
        int mt = idx >> 2, kt = idx & 3;
        int gm = mg[mt];
        if (gm >= 0 && gm == mg[kt]){
          short8 a = *(const short8*)&qb[mt*16 + c][h*32 + hi*8];
          short8 b = *(const short8*)&kb[kt*16 + c][h*32 + hi*8];
          f32x4 acc = {0.f, 0.f, 0.f, 0.f};
          acc = __builtin_amdgcn_mfma_f32_16x16x32_bf16(a, b, acc, 0,0,0);
          #pragma unroll
          for (int r = 0; r < 4; r++) sc[mt*16 + hi*4 + r][kt*16 + c] = f2bs(acc[r] * ISQ);
        }
      }
      __syncthreads();
      // masked softmax in-place: 4 threads per row, group-reduce
      {
        int row = t >> 2, q4 = t & 3;
        int s = row >> 4;
        if (mg[s] >= 0){
          int kbeg = mbase[s]*16;
          int kend = kbeg + mL[s];
          int send = kbeg + (((mL[s] + 15) >> 4) << 4);
          int b0 = q4*16;
          float e[16];
          float mx = -3.4e38f;
          #pragma unroll
          for (int kk = 0; kk < 16; ++kk){
            int col = b0 + kk;
            bool ok = (col >= kbeg) && (col < kend);
            float lg = ok ? b2f(sc[row][col]) : -3.4e38f;
            e[kk] = lg;
            mx = fmaxf(mx, lg);
          }
          mx = fmaxf(mx, __shfl_xor(mx, 1));
          mx = fmaxf(mx, __shfl_xor(mx, 2));
          float sm = 0.f;
          #pragma unroll
          for (int kk = 0; kk < 16; ++kk){
            int col = b0 + kk;
            bool ok = (col >= kbeg) && (col < kend);
            float ee = ok ? __expf(e[kk] - mx) : 0.f;
            e[kk] = ee; sm += ee;
          }
          sm += __shfl_xor(sm, 1);
          sm += __shfl_xor(sm, 2);
          float inv = 1.f / sm;
          #pragma unroll
          for (int kk = 0; kk < 16; ++kk){
            int col = b0 + kk;
            if (col >= kbeg && col < send)
              sc[row][col] = f2bs((col < kend) ? e[kk]*inv : 0.f);
          }
        }
      }
      __syncthreads();
      // PV -> overwrite Q columns of this head in qb
      for (int idx = w; idx < 8; idx += 4){
        int mt = idx >> 1, dt = idx & 1;
        if (mg[mt] >= 0){
          f32x4 acc = {0.f, 0.f, 0.f, 0.f};
          #pragma unroll
          for (int ks = 0; ks < 2; ++ks){
            short8 a = *(const short8*)&sc[mt*16 + c][ks*32 + hi*8];
            short8 b = *(const short8*)&vt[h*32 + dt*16 + c][ks*32 + hi*8];
            acc = __builtin_amdgcn_mfma_f32_16x16x32_bf16(a, b, acc, 0,0,0);
          }
          int col = h*32 + dt*16 + c;
          #pragma unroll
          for (int r = 0; r < 4; r++) qb[mt*16 + hi*4 + r][col] = f2bs(acc[r]);
        }
      }
      __syncthreads();
    }

    // ---- Wo + bo + residual -> xb ----
    {
      short8 aw[4];
      #pragma unroll
      for (int kk = 0; kk < 4; kk++) aw[kk] = *(const short8*)&qb[w*16 + c][kk*32 + hi*8];
      const short* wfo = wfrag + (size_t)(3*4 + blk)*16384;
      #pragma unroll 2
      for (int nt = 0; nt < 8; ++nt){
        int col = nt*16 + c;
        f32x4 acc = mfma4(aw[0], aw[1], aw[2], aw[3], wfo, nt, l);
        float bb = bo[blk*C + col];
        #pragma unroll
        for (int r = 0; r < 4; r++){
          int row = w*16 + hi*4 + r;
          xb[row][col] = f2bs(acc[r] + bb + b2f(xb[row][col]));
        }
      }
    }
    __syncthreads();
    ln_rows(xb, xb, g1 + blk*C, b1 + blk*C, t);
    __syncthreads();

    // ---- FF -> kb ----
    {
      short8 aw[4];
      #pragma unroll
      for (int kk = 0; kk < 4; kk++) aw[kk] = *(const short8*)&xb[w*16 + c][kk*32 + hi*8];
      const short* wfl = wfrag + (size_t)(4*4 + blk)*16384;
      #pragma unroll 2
      for (int nt = 0; nt < 8; ++nt){
        int col = nt*16 + c;
        f32x4 acc = mfma4(aw[0], aw[1], aw[2], aw[3], wfl, nt, l);
        float bb = blin[blk*C + col];
        #pragma unroll
        for (int r = 0; r < 4; r++){
          int row = w*16 + hi*4 + r;
          kb[row][col] = f2bs(b2f(xb[row][col]) + fmaxf(acc[r] + bb, 0.f));
        }
      }
    }
    __syncthreads();
    ln_rows(kb, xb, g2 + blk*C, b2 + blk*C, t);
    __syncthreads();
  }

  // ================= PMA: K,V projections + per-gene pooling =================
  {
    short8 aw[4];
    #pragma unroll
    for (int kk = 0; kk < 4; kk++) aw[kk] = *(const short8*)&xb[w*16 + c][kk*32 + hi*8];
    const short* wfk2 = wfrag + (size_t)(1*4 + 2)*16384;
    const short* wfv2 = wfrag + (size_t)(2*4 + 2)*16384;
    #pragma unroll 2
    for (int nt = 0; nt < 8; ++nt){
      int col = nt*16 + c;
      f32x4 acc = mfma4(aw[0], aw[1], aw[2], aw[3], wfk2, nt, l);
      float bb = bk[2*C + col];
      #pragma unroll
      for (int r = 0; r < 4; r++) kb[w*16 + hi*4 + r][col] = f2bs(acc[r] + bb);
      acc = mfma4(aw[0], aw[1], aw[2], aw[3], wfv2, nt, l);
      bb = bv[2*C + col];
      short4v pk;
      #pragma unroll
      for (int r = 0; r < 4; r++) pk[r] = f2bs(acc[r] + bb);
      *(short4v*)&vt[col][w*16 + hi*4] = pk;
    }
  }
  __syncthreads();
  // pooling: wave w = slot w (if base slot of a gene)
  {
    int g = mg[w];
    if (g >= 0 && mbase[w] == w){
      int L = mL[w];
      int row = w*16 + l;                // key row in kb / key col in vt
      float* ps = (float*)&sc[0][0];     // sc dead: alias as fp32 probs [slot*4+h][64]
      #pragma unroll
      for (int h = 0; h < 4; ++h){
        float a = -3.4e38f;
        if (l < L){
          float acc = 0.f;
          #pragma unroll 8
          for (int dd = 0; dd < 32; ++dd)
            acc = fmaf(b2f(kb[row][h*32 + dd]), qrl[h*32 + dd], acc);
          a = acc * ISQ;
        }
        float mx = wmax(a);
        float e = (l < L) ? __expf(a - mx) : 0.f;
        float s = wsum(e);
        ps[(w*4 + h)*64 + l] = e / s;
      }
      #pragma unroll
      for (int half = 0; half < 2; ++half){
        int d = l + half*64;
        int h = d >> 5;
        float acc = 0.f;
        for (int kk = 0; kk < L; ++kk)
          acc = fmaf(ps[(w*4 + h)*64 + kk], b2f(vt[d][w*16 + kk]), acc);
        pooled[(size_t)g*C + d] = acc;
      }
    }
  }
}

// ================= PMA tail + decoder SAB (per gene) =================
__global__ __launch_bounds__(256) void tail_kernel(
  const float* __restrict__ pooled,
  const float* __restrict__ Wv, const float* __restrict__ Wo,
  const float* __restrict__ Wlin,
  const float* __restrict__ bv, const float* __restrict__ bo,
  const float* __restrict__ blin,
  const float* __restrict__ g1, const float* __restrict__ b1,
  const float* __restrict__ g2, const float* __restrict__ b2,
  const float* __restrict__ seed, float* __restrict__ out)
{
  __shared__ float row0[C], row1[C], row2[C];
  const int g = blockIdx.x, t = threadIdx.x, w = t >> 6, l = t & 63;
  if (t < C) row1[t] = pooled[(size_t)g*C + t];
  __syncthreads();
  if (t < C){ // y = attn @ Wo2 + bo2 + seed -> row0
    float acc = bo[2*C + t];
    const float* wo2 = Wo + 2*C*C;
    #pragma unroll 4
    for (int k = 0; k < C; k++) acc = fmaf(row1[k], wo2[k*C + t], acc);
    row0[t] = acc + seed[t];
  }
  __syncthreads();
  if (w == 0){ // LN1
    float v0 = row0[l], v1 = row0[l + 64];
    float m = wsum(v0 + v1) * (1.f / C);
    float d0 = v0 - m, d1 = v1 - m;
    float va = wsum(d0*d0 + d1*d1) * (1.f / C);
    float rs = rsqrtf(va + EPS);
    row0[l]      = d0 * rs * g1[2*C + l]      + b1[2*C + l];
    row0[l + 64] = d1 * rs * g1[2*C + l + 64] + b1[2*C + l + 64];
  }
  __syncthreads();
  if (t < C){ // FF -> row1
    float acc = blin[2*C + t];
    const float* wl2 = Wlin + 2*C*C;
    #pragma unroll 4
    for (int k = 0; k < C; k++) acc = fmaf(row0[k], wl2[k*C + t], acc);
    row1[t] = row0[t] + fmaxf(acc, 0.f);
  }
  __syncthreads();
  if (w == 0){ // LN2 -> row0 = h3
    float v0 = row1[l], v1 = row1[l + 64];
    float m = wsum(v0 + v1) * (1.f / C);
    float d0 = v0 - m, d1 = v1 - m;
    float va = wsum(d0*d0 + d1*d1) * (1.f / C);
    float rs = rsqrtf(va + EPS);
    row0[l]      = d0 * rs * g2[2*C + l]      + b2[2*C + l];
    row0[l + 64] = d1 * rs * g2[2*C + l + 64] + b2[2*C + l + 64];
  }
  __syncthreads();
  // decoder SAB (Lq=Lk=1, softmax(1)=1)
  {
    const float* wv3 = Wv + 3*C*C; const float* wo3 = Wo + 3*C*C; const float* wl3 = Wlin + 3*C*C;
    if (t < C){
      float acc = bv[3*C + t];
      #pragma unroll 4
      for (int k = 0; k < C; k++) acc = fmaf(row0[k], wv3[k*C + t], acc);
      row1[t] = acc;
    }
    __syncthreads();
    if (t < C){
      float acc = bo[3*C + t];
      #pragma unroll 4
      for (int k = 0; k < C; k++) acc = fmaf(row1[k], wo3[k*C + t], acc);
      row2[t] = acc + row0[t];
    }
    __syncthreads();
    if (w == 0){
      float v0 = row2[l], v1 = row2[l + 64];
      float m = wsum(v0 + v1) * (1.f / C);
      float d0 = v0 - m, d1 = v1 - m;
      float va = wsum(d0*d0 + d1*d1) * (1.f / C);
      float rs = rsqrtf(va + EPS);
      row2[l]      = d0 * rs * g1[3*C + l]      + b1[3*C + l];
      row2[l + 64] = d1 * rs * g1[3*C + l + 64] + b1[3*C + l + 64];
    }
    __syncthreads();
    if (t < C){
      float acc = blin[3*C + t];
      #pragma unroll 4
      for (int k = 0; k < C; k++) acc = fmaf(row2[k], wl3[k*C + t], acc);
      row1[t] = row2[t] + fmaxf(acc, 0.f);
    }
    __syncthreads();
    if (w == 0){
      float v0 = row1[l], v1 = row1[l + 64];
      float m = wsum(v0 + v1) * (1.f / C);
      float d0 = v0 - m, d1 = v1 - m;
      float va = wsum(d0*d0 + d1*d1) * (1.f / C);
      float rs = rsqrtf(va + EPS);
      float r0 = d0 * rs * g2[3*C + l]      + b2[3*C + l];
      float r1 = d1 * rs * g2[3*C + l + 64] + b2[3*C + l + 64];
      if (isnan(r0)) r0 = 0.f; else if (isinf(r0)) r0 = r0 > 0 ? 3.402823466e38f : -3.402823466e38f;
      if (isnan(r1)) r1 = 0.f; else if (isinf(r1)) r1 = r1 > 0 ? 3.402823466e38f : -3.402823466e38f;
      out[(size_t)g*C + l]      = r0;
      out[(size_t)g*C + l + 64] = r1;
    }
  }
}

extern "C" void kernel_launch(void* const* d_in, const int* in_sizes, int n_in,
                              void* d_out, int out_size, void* d_ws, size_t ws_size,
                              hipStream_t stream){
  const float* RF   = (const float*)d_in[0];
  const float* Wq   = (const float*)d_in[1];
  const float* Wk   = (const float*)d_in[2];
  const float* Wv   = (const float*)d_in[3];
  const float* Wo   = (const float*)d_in[4];
  const float* bq   = (const float*)d_in[5];
  const float* bk   = (const float*)d_in[6];
  const float* bv   = (const float*)d_in[7];
  const float* bo   = (const float*)d_in[8];
  const float* Wlin = (const float*)d_in[9];
  const float* blin = (const float*)d_in[10];
  const float* g1   = (const float*)d_in[11];
  const float* b1   = (const float*)d_in[12];
  const float* g2   = (const float*)d_in[13];
  const float* b2   = (const float*)d_in[14];
  const float* seed = (const float*)d_in[15];
  const int* rxn    = (const int*)d_in[16];
  const int* gidx   = (const int*)d_in[17];

  int E = in_sizes[16];
  int G = out_size / C;

  // ws layout
  char* base = (char*)d_ws;
  short* wfrag = (short*)base;                             // 655360 B
  float* qrow  = (float*)(base + 655360);                  // 512 B
  int*   meta  = (int*)(base + 655872);                    // 64 B: [0]=nbins, [1..4]=cnt
  int*   starts= (int*)(base + 655936);                    // 4G
  int*   counts= (int*)(base + 655936 + (size_t)4*G);      // 4G
  int*   gcr   = (int*)(base + 655936 + (size_t)8*G);      // 4G
  int*   binfo = (int*)(base + 655936 + (size_t)12*G);     // 16G
  float* pooled= (float*)(base + 655936 + (size_t)28*G);   // 512G

  hipMemsetAsync(meta, 0, 64, stream);
  hipMemsetAsync(binfo, 0xFF, (size_t)16*G, stream);
  prep_wfrag<<<640, 64, 0, stream>>>(Wq, Wk, Wv, Wo, Wlin, wfrag);
  prep_qrow<<<1, 128, 0, stream>>>(seed, Wq, bq, qrow);
  seg_kernel<<<(G + 255)/256, 256, 0, stream>>>(gidx, E, G, starts, counts, meta + 1, gcr);
  fill_kernel<<<(G + 255)/256, 256, 0, stream>>>(G, meta + 1, gcr, binfo, meta);
  gene_bin_kernel<<<G, 256, 0, stream>>>(RF, wfrag, qrow, bq, bk, bv, bo, blin,
      g1, b1, g2, b2, rxn, starts, counts, binfo, meta, pooled);
  tail_kernel<<<G, 256, 0, stream>>>(pooled, Wv, Wo, Wlin, bv, bo, blin,
      g1, b1, g2, b2, seed, (float*)d_out);
}

// Round 6
// 309.232 us; speedup vs baseline: 11.0603x; 1.0030x over previous
//
#include <hip/hip_runtime.h>
#include <hip/hip_bf16.h>
#include <math.h>

#define C 128
#define LMAX 64
#define EPS 1e-5f
#define ISQ 0.17677669529663687f   // 1/sqrt(32)

using short8  = __attribute__((ext_vector_type(8))) short;
using f32x4   = __attribute__((ext_vector_type(4))) float;

#define WSYNC() do { asm volatile("s_waitcnt lgkmcnt(0)" ::: "memory"); __builtin_amdgcn_sched_barrier(0); } while(0)

__device__ __forceinline__ float wsum(float v){
  #pragma unroll
  for (int o = 32; o > 0; o >>= 1) v += __shfl_xor(v, o, 64);
  return v;
}
__device__ __forceinline__ float wmax(float v){
  #pragma unroll
  for (int o = 32; o > 0; o >>= 1) v = fmaxf(v, __shfl_xor(v, o, 64));
  return v;
}
__device__ __forceinline__ short f2bs(float f){
  __hip_bfloat16 b = __float2bfloat16(f);   // RNE
  union { __hip_bfloat16 b; short u; } cv; cv.b = b; return cv.u;
}
__device__ __forceinline__ float b2f(short u){
  return __uint_as_float(((unsigned)(unsigned short)u) << 16);
}
__device__ __forceinline__ unsigned pack2(float a, float b){
  return (unsigned)(unsigned short)f2bs(a) | ((unsigned)(unsigned short)f2bs(b) << 16);
}

// ---- weight fragments: B-operand layout for mfma_f32_16x16x32_bf16 ----
// lane l, j -> W[kt*32 + (l>>4)*8 + j][nt*16 + (l&15)]
__global__ void prep_wfrag(const float* __restrict__ Wq, const float* __restrict__ Wk,
                           const float* __restrict__ Wv, const float* __restrict__ Wo,
                           const float* __restrict__ Wlin, short* __restrict__ wf){
  int bid = blockIdx.x, l = threadIdx.x;
  int tile = bid & 31, mb = bid >> 5;       // mb = mat*4+blk, 0..19
  int mat = mb >> 2, blk = mb & 3;
  const float* W = (mat==0?Wq : mat==1?Wk : mat==2?Wv : mat==3?Wo : Wlin) + blk*C*C;
  int nt = tile >> 2, kt = tile & 3;
  int col = nt*16 + (l & 15);
  int k0  = kt*32 + ((l >> 4) << 3);
  short8 v;
  #pragma unroll
  for (int j = 0; j < 8; j++) v[j] = f2bs(W[(k0 + j)*C + col]);
  *(short8*)(wf + ((size_t)mb*32 + tile)*512 + (size_t)l*8) = v;
}

__global__ void prep_qrow(const float* __restrict__ seed, const float* __restrict__ Wq,
                          const float* __restrict__ bq, float* __restrict__ qrow){
  int t = threadIdx.x;
  const float* wq2 = Wq + 2*C*C;
  float acc = bq[2*C + t];
  #pragma unroll 4
  for (int k = 0; k < C; k++) acc = fmaf(seed[k], wq2[k*C + t], acc);
  qrow[t] = acc;
}

// ---- segment bounds + class ranks ----
__global__ void seg_kernel(const int* __restrict__ gidx, int E, int G,
                           int* __restrict__ starts, int* __restrict__ counts,
                           int* __restrict__ cnt, int* __restrict__ gcr){
  int g = blockIdx.x * blockDim.x + threadIdx.x;
  if (g >= G) return;
  int lo = 0, hi = E;
  while (lo < hi){ int m = (lo + hi) >> 1; if (gidx[m] < g) lo = m + 1; else hi = m; }
  int s = lo; hi = E;
  while (lo < hi){ int m = (lo + hi) >> 1; if (gidx[m] < g + 1) lo = m + 1; else hi = m; }
  starts[g] = s;
  int c_ = lo - s; counts[g] = c_;
  int L = c_ > LMAX ? LMAX : c_; if (L < 1) L = 1;
  int cl = (L - 1) >> 4;
  int r = atomicAdd(&cnt[cl], 1);
  gcr[g] = (cl << 28) | r;
}

__global__ void fill_kernel(int G, const int* __restrict__ cnt, const int* __restrict__ gcr,
                            int* __restrict__ binfo, int* __restrict__ nbins){
  int g = blockIdx.x * blockDim.x + threadIdx.x;
  if (g >= G) return;
  int nb1 = (cnt[0] + 3) >> 2, nb2 = (cnt[1] + 1) >> 1, nb3 = cnt[2];
  if (g == 0) *nbins = nb1 + nb2 + nb3 + cnt[3];
  int v = gcr[g]; int cl = v >> 28; int r = v & 0x0FFFFFFF;
  int bin, slot;
  if      (cl == 0){ bin = r >> 2;             slot = r & 3; }
  else if (cl == 1){ bin = nb1 + (r >> 1);     slot = (r & 1) * 2; }
  else if (cl == 2){ bin = nb1 + nb2 + r;      slot = 0; }
  else             { bin = nb1 + nb2 + nb3 + r; slot = 0; }
  binfo[bin*4 + slot] = g;
}

__device__ __forceinline__ f32x4 mfma4(short8 a0, short8 a1, short8 a2, short8 a3,
                                       const short* __restrict__ wf, int nt, int l){
  f32x4 acc = {0.f, 0.f, 0.f, 0.f};
  acc = __builtin_amdgcn_mfma_f32_16x16x32_bf16(a0, *(const short8*)(wf + ((nt*4+0)*64 + l)*8), acc, 0,0,0);
  acc = __builtin_amdgcn_mfma_f32_16x16x32_bf16(a1, *(const short8*)(wf + ((nt*4+1)*64 + l)*8), acc, 0,0,0);
  acc = __builtin_amdgcn_mfma_f32_16x16x32_bf16(a2, *(const short8*)(wf + ((nt*4+2)*64 + l)*8), acc, 0,0,0);
  acc = __builtin_amdgcn_mfma_f32_16x16x32_bf16(a3, *(const short8*)(wf + ((nt*4+3)*64 + l)*8), acc, 0,0,0);
  return acc;
}

// in-register LN on D-layout regs v[nt][r]: row = (16-lane group), reduce via shfl 1,2,4,8 + nt regs
__device__ __forceinline__ void ln_inreg(float (&v)[8][4], const float (&gv)[8], const float (&bv)[8]){
  #pragma unroll
  for (int r = 0; r < 4; ++r){
    float s = 0.f;
    #pragma unroll
    for (int nt = 0; nt < 8; ++nt) s += v[nt][r];
    s += __shfl_xor(s,1); s += __shfl_xor(s,2); s += __shfl_xor(s,4); s += __shfl_xor(s,8);
    float mean = s * (1.f/128.f);
    float q = 0.f;
    #pragma unroll
    for (int nt = 0; nt < 8; ++nt){ float d = v[nt][r] - mean; q += d*d; }
    q += __shfl_xor(q,1); q += __shfl_xor(q,2); q += __shfl_xor(q,4); q += __shfl_xor(q,8);
    float rs = rsqrtf(q*(1.f/128.f) + EPS);
    #pragma unroll
    for (int nt = 0; nt < 8; ++nt) v[nt][r] = (v[nt][r] - mean)*rs*gv[nt] + bv[nt];
  }
}

__global__ __launch_bounds__(256, 3) void gene_bin_kernel(
  const float* __restrict__ RF, const short* __restrict__ wfrag,
  const float* __restrict__ qrow,
  const float* __restrict__ bq, const float* __restrict__ bk,
  const float* __restrict__ bv, const float* __restrict__ bo,
  const float* __restrict__ blin,
  const float* __restrict__ g1, const float* __restrict__ b1,
  const float* __restrict__ g2, const float* __restrict__ b2,
  const int* __restrict__ rxn_idx, const int* __restrict__ starts,
  const int* __restrict__ counts, const int* __restrict__ binfo,
  const int* __restrict__ meta, float* __restrict__ pooled)
{
  __shared__ short xb[64][138];   // activations / Q / P staging
  __shared__ short kb[64][138];   // K / O staging / FF staging / PMA K'
  __shared__ short vt[128][74];   // V^T: vt[d][key]
  __shared__ int mg[4], mL[4], ms0[4], mbase[4];

  if ((int)blockIdx.x >= meta[0]) return;
  const int bin = blockIdx.x;
  const int t = threadIdx.x, w = t >> 6, l = t & 63;
  const int hi = l >> 4, c = l & 15;
  const int r0 = w * 16;

  if (t == 0){
    int s = 0;
    while (s < 4){
      int g = binfo[bin*4 + s];
      if (g >= 0){
        int Lg = counts[g]; if (Lg > LMAX) Lg = LMAX;
        int ntg = (Lg + 15) >> 4;
        for (int u = 0; u < ntg; ++u){ mg[s+u] = g; mL[s+u] = Lg; ms0[s+u] = starts[g]; mbase[s+u] = s; }
        s += ntg;
      } else { mg[s] = -1; mL[s] = 0; ms0[s] = 0; mbase[s] = s; s++; }
    }
  }
  __syncthreads();

  // ---- stage rows (bf16), zero pad rows ----
  for (int idx = t; idx < 64*16; idx += 256){
    int row = idx >> 4, ch = idx & 15;
    int s = row >> 4;
    int g = mg[s];
    int ro = row - mbase[s]*16;
    short8 u = {0,0,0,0,0,0,0,0};
    if (g >= 0 && ro < mL[s]){
      int rr = rxn_idx[ms0[s] + ro];
      const float* src = RF + (size_t)rr*C + ch*8;
      float4 v0 = *(const float4*)(src);
      float4 v1 = *(const float4*)(src + 4);
      u[0]=f2bs(v0.x); u[1]=f2bs(v0.y); u[2]=f2bs(v0.z); u[3]=f2bs(v0.w);
      u[4]=f2bs(v1.x); u[5]=f2bs(v1.y); u[6]=f2bs(v1.z); u[7]=f2bs(v1.w);
    }
    *(short8*)&xb[row][ch*8] = u;
  }
  __syncthreads();

  const int myg  = mg[w];
  const int kbeg = mbase[w]*16;
  const int kend = kbeg + mL[w];

  // residual (D-pattern) from staged input
  float resid[8][4];
  #pragma unroll
  for (int nt = 0; nt < 8; ++nt)
    #pragma unroll
    for (int r = 0; r < 4; ++r)
      resid[nt][r] = b2f(xb[r0 + hi*4 + r][nt*16 + c]);
  WSYNC();

  // ================= encoder SABs (blk 0,1) =================
  #pragma unroll 1
  for (int blk = 0; blk < 2; ++blk){
    const short* wfq = wfrag + (size_t)(0*4 + blk)*16384;
    const short* wfk = wfrag + (size_t)(1*4 + blk)*16384;
    const short* wfv = wfrag + (size_t)(2*4 + blk)*16384;
    const short* wfo = wfrag + (size_t)(3*4 + blk)*16384;
    const short* wfl = wfrag + (size_t)(4*4 + blk)*16384;

    // ---- QKV (wave-local rows); Q staged into own xb rows ----
    {
      short8 ax[4];
      #pragma unroll
      for (int kk = 0; kk < 4; ++kk) ax[kk] = *(const short8*)&xb[r0 + c][kk*32 + hi*8];
      WSYNC();
      #pragma unroll
      for (int nt = 0; nt < 8; ++nt){
        int col = nt*16 + c;
        f32x4 aq = mfma4(ax[0],ax[1],ax[2],ax[3], wfq, nt, l);
        f32x4 ak = mfma4(ax[0],ax[1],ax[2],ax[3], wfk, nt, l);
        f32x4 av = mfma4(ax[0],ax[1],ax[2],ax[3], wfv, nt, l);
        float bqv = bq[blk*C + col], bkv = bk[blk*C + col], bvv = bv[blk*C + col];
        #pragma unroll
        for (int r = 0; r < 4; ++r){
          kb[r0 + hi*4 + r][col] = f2bs(ak[r] + bkv);
          vt[col][r0 + hi*4 + r] = f2bs(av[r] + bvv);
          xb[r0 + hi*4 + r][col] = f2bs(aq[r] + bqv);
        }
      }
    }
    __syncthreads();   // bar A: K,V visible block-wide

    // ---- scores + in-register softmax for all 4 heads ----
    unsigned pp[4][8];
    #pragma unroll
    for (int h = 0; h < 4; ++h){
      short8 qa = *(const short8*)&xb[r0 + c][h*32 + hi*8];
      f32x4 lg[4];
      #pragma unroll
      for (int kt = 0; kt < 4; ++kt){
        f32x4 z = {0.f,0.f,0.f,0.f};
        if (myg >= 0 && mg[kt] == myg)
          z = __builtin_amdgcn_mfma_f32_16x16x32_bf16(qa,
                *(const short8*)&kb[kt*16 + c][h*32 + hi*8], z, 0,0,0);
        lg[kt] = z;
      }
      float P[4][4];
      #pragma unroll
      for (int r = 0; r < 4; ++r){
        float mx = -3.4e38f;
        #pragma unroll
        for (int kt = 0; kt < 4; ++kt){
          int col = kt*16 + c;
          bool ok = (col >= kbeg) && (col < kend);
          float v = ok ? lg[kt][r]*ISQ : -3.4e38f;
          P[kt][r] = v;
          mx = fmaxf(mx, v);
        }
        mx = fmaxf(mx, __shfl_xor(mx,1)); mx = fmaxf(mx, __shfl_xor(mx,2));
        mx = fmaxf(mx, __shfl_xor(mx,4)); mx = fmaxf(mx, __shfl_xor(mx,8));
        float sm = 0.f;
        #pragma unroll
        for (int kt = 0; kt < 4; ++kt){
          int col = kt*16 + c;
          bool ok = (col >= kbeg) && (col < kend);
          float e = ok ? __expf(P[kt][r] - mx) : 0.f;
          P[kt][r] = e; sm += e;
        }
        sm += __shfl_xor(sm,1); sm += __shfl_xor(sm,2);
        sm += __shfl_xor(sm,4); sm += __shfl_xor(sm,8);
        float inv = (sm > 0.f) ? 1.f/sm : 0.f;
        #pragma unroll
        for (int kt = 0; kt < 4; ++kt) P[kt][r] *= inv;
      }
      #pragma unroll
      for (int kt = 0; kt < 4; ++kt){
        pp[h][kt*2+0] = pack2(P[kt][0], P[kt][1]);
        pp[h][kt*2+1] = pack2(P[kt][2], P[kt][3]);
      }
    }
    __syncthreads();   // bar B: all K reads complete

    // ---- PV in head pairs: P staged over dead Q rows (wave-local) ----
    f32x4 O[8];
    {
      f32x4 zz = {0.f,0.f,0.f,0.f};
      #pragma unroll
      for (int nt = 0; nt < 8; ++nt) O[nt] = zz;
    }
    #pragma unroll
    for (int pr = 0; pr < 2; ++pr){
      #pragma unroll
      for (int hh = 0; hh < 2; ++hh){
        int h = pr*2 + hh;
        #pragma unroll
        for (int kt = 0; kt < 4; ++kt)
          #pragma unroll
          for (int r = 0; r < 4; ++r){
            unsigned u = pp[h][kt*2 + (r>>1)];
            xb[r0 + hi*4 + r][hh*64 + kt*16 + c] = (short)((r&1) ? (u >> 16) : (u & 0xFFFF));
          }
      }
      WSYNC();
      #pragma unroll
      for (int hh = 0; hh < 2; ++hh){
        int h = pr*2 + hh;
        #pragma unroll
        for (int dt = 0; dt < 2; ++dt){
          f32x4 acc = O[h*2 + dt];
          #pragma unroll
          for (int ks = 0; ks < 2; ++ks){
            if (kend > ks*32 && kbeg < ks*32 + 32){
              short8 a = *(const short8*)&xb[r0 + c][hh*64 + ks*32 + hi*8];
              short8 b = *(const short8*)&vt[h*32 + dt*16 + c][ks*32 + hi*8];
              acc = __builtin_amdgcn_mfma_f32_16x16x32_bf16(a, b, acc, 0,0,0);
            }
          }
          O[h*2 + dt] = acc;
        }
      }
      WSYNC();
    }

    // ---- Wo + bias + residual, LN1 (in-reg), FF, LN2 (in-reg) ----
    #pragma unroll
    for (int nt = 0; nt < 8; ++nt)
      #pragma unroll
      for (int r = 0; r < 4; ++r)
        kb[r0 + hi*4 + r][nt*16 + c] = f2bs(O[nt][r]);
    WSYNC();
    short8 af[4];
    #pragma unroll
    for (int kk = 0; kk < 4; ++kk) af[kk] = *(const short8*)&kb[r0 + c][kk*32 + hi*8];
    float y[8][4];
    float g1v[8], b1v[8], g2v[8], b2v[8];
    #pragma unroll
    for (int nt = 0; nt < 8; ++nt){
      int col = nt*16 + c;
      g1v[nt] = g1[blk*C + col]; b1v[nt] = b1[blk*C + col];
      g2v[nt] = g2[blk*C + col]; b2v[nt] = b2[blk*C + col];
      f32x4 acc = mfma4(af[0],af[1],af[2],af[3], wfo, nt, l);
      float bb = bo[blk*C + col];
      #pragma unroll
      for (int r = 0; r < 4; ++r) y[nt][r] = acc[r] + bb + resid[nt][r];
    }
    ln_inreg(y, g1v, b1v);
    #pragma unroll
    for (int nt = 0; nt < 8; ++nt)
      #pragma unroll
      for (int r = 0; r < 4; ++r)
        kb[r0 + hi*4 + r][nt*16 + c] = f2bs(y[nt][r]);
    WSYNC();
    short8 af2[4];
    #pragma unroll
    for (int kk = 0; kk < 4; ++kk) af2[kk] = *(const short8*)&kb[r0 + c][kk*32 + hi*8];
    float ff[8][4];
    #pragma unroll
    for (int nt = 0; nt < 8; ++nt){
      int col = nt*16 + c;
      f32x4 acc = mfma4(af2[0],af2[1],af2[2],af2[3], wfl, nt, l);
      float bb = blin[blk*C + col];
      #pragma unroll
      for (int r = 0; r < 4; ++r) ff[nt][r] = y[nt][r] + fmaxf(acc[r] + bb, 0.f);
    }
    ln_inreg(ff, g2v, b2v);
    #pragma unroll
    for (int nt = 0; nt < 8; ++nt)
      #pragma unroll
      for (int r = 0; r < 4; ++r){
        xb[r0 + hi*4 + r][nt*16 + c] = f2bs(ff[nt][r]);
        resid[nt][r] = ff[nt][r];
      }
    __syncthreads();   // bar C: vt/kb reads of this block complete
  }

  // ================= PMA: K',V' projections + per-gene pooling =================
  {
    const short* wfk2 = wfrag + (size_t)(1*4 + 2)*16384;
    const short* wfv2 = wfrag + (size_t)(2*4 + 2)*16384;
    short8 ax[4];
    #pragma unroll
    for (int kk = 0; kk < 4; ++kk) ax[kk] = *(const short8*)&xb[r0 + c][kk*32 + hi*8];
    #pragma unroll
    for (int nt = 0; nt < 8; ++nt){
      int col = nt*16 + c;
      f32x4 ak = mfma4(ax[0],ax[1],ax[2],ax[3], wfk2, nt, l);
      f32x4 av = mfma4(ax[0],ax[1],ax[2],ax[3], wfv2, nt, l);
      float bkv = bk[2*C + col], bvv = bv[2*C + col];
      #pragma unroll
      for (int r = 0; r < 4; ++r){
        kb[r0 + hi*4 + r][col] = f2bs(ak[r] + bkv);
        vt[col][r0 + hi*4 + r] = f2bs(av[r] + bvv);
      }
    }
  }
  __syncthreads();   // bar A': K',V' visible

  if (myg >= 0 && mbase[w] == w){
    int L = mL[w];
    float* ps = (float*)&xb[0][0];   // xb dead
    #pragma unroll
    for (int h = 0; h < 4; ++h){
      float a = -3.4e38f;
      if (l < L){
        float acc = 0.f;
        #pragma unroll 8
        for (int dd = 0; dd < 32; ++dd)
          acc = fmaf(b2f(kb[r0 + l][h*32 + dd]), qrow[h*32 + dd], acc);
        a = acc * ISQ;
      }
      float mx = wmax(a);
      float e = (l < L) ? __expf(a - mx) : 0.f;
      float s = wsum(e);
      float inv = (s > 0.f) ? 1.f/s : 0.f;
      ps[(w*4 + h)*64 + l] = e * inv;
    }
    WSYNC();
    #pragma unroll
    for (int half = 0; half < 2; ++half){
      int d = l + half*64;
      int h = d >> 5;
      float acc = 0.f;
      for (int kk = 0; kk < L; ++kk)
        acc = fmaf(ps[(w*4 + h)*64 + kk], b2f(vt[d][r0 + kk]), acc);
      pooled[(size_t)myg*C + d] = acc;
    }
  }
}

// ================= fp32 batched tail: PMA post-attn + decoder SAB (16 genes/block) =================
__device__ __forceinline__ void gemmf(const float (*src)[132], const float* __restrict__ W,
                                      float (&o)[8], int col, int rg){
  #pragma unroll
  for (int r = 0; r < 8; ++r) o[r] = 0.f;
  #pragma unroll 4
  for (int k = 0; k < 128; ++k){
    float wv = W[k*C + col];
    #pragma unroll
    for (int r = 0; r < 8; ++r) o[r] = fmaf(src[rg*8 + r][k], wv, o[r]);
  }
}

__device__ __forceinline__ void ln16f(float (*buf)[132], const float* __restrict__ gg,
                                      const float* __restrict__ bb, int t){
  int row = t >> 4, cg = t & 15;
  float v[8]; float s = 0.f;
  #pragma unroll
  for (int k = 0; k < 8; ++k){ v[k] = buf[row][cg*8 + k]; s += v[k]; }
  s += __shfl_xor(s,1); s += __shfl_xor(s,2); s += __shfl_xor(s,4); s += __shfl_xor(s,8);
  float mean = s * (1.f/128.f);
  float q = 0.f;
  #pragma unroll
  for (int k = 0; k < 8; ++k){ float d = v[k] - mean; q += d*d; }
  q += __shfl_xor(q,1); q += __shfl_xor(q,2); q += __shfl_xor(q,4); q += __shfl_xor(q,8);
  float rs = rsqrtf(q*(1.f/128.f) + EPS);
  #pragma unroll
  for (int k = 0; k < 8; ++k)
    buf[row][cg*8 + k] = (v[k] - mean)*rs*gg[cg*8 + k] + bb[cg*8 + k];
}

__global__ __launch_bounds__(256) void tail_kernel(
  const float* __restrict__ pooled,
  const float* __restrict__ Wv, const float* __restrict__ Wo,
  const float* __restrict__ Wlin,
  const float* __restrict__ bv, const float* __restrict__ bo,
  const float* __restrict__ blin,
  const float* __restrict__ g1, const float* __restrict__ b1,
  const float* __restrict__ g2, const float* __restrict__ b2,
  const float* __restrict__ seed, float* __restrict__ out, int G)
{
  __shared__ float ta[16][132];
  __shared__ float tb[16][132];
  const int t = threadIdx.x;
  const int g0 = blockIdx.x * 16;
  const int col = t & 127, rg = t >> 7;   // 8 rows per thread
  float o[8], res[8];

  { // load pooled -> ta
    int row = t >> 4, ch = t & 15;
    float4 v0 = {0,0,0,0}, v1 = {0,0,0,0};
    if (g0 + row < G){
      const float* src = pooled + (size_t)(g0 + row)*C + ch*8;
      v0 = *(const float4*)(src);
      v1 = *(const float4*)(src + 4);
    }
    *(float4*)&ta[row][ch*8] = v0;
    *(float4*)&ta[row][ch*8 + 4] = v1;
  }
  __syncthreads();

  // P1: y = pooled @ Wo2 + bo2 + seed -> tb ; LN1
  gemmf(ta, Wo + 2*C*C, o, col, rg);
  {
    float ss = seed[col], bb = bo[2*C + col];
    #pragma unroll
    for (int r = 0; r < 8; ++r) tb[rg*8 + r][col] = o[r] + bb + ss;
  }
  __syncthreads();
  ln16f(tb, g1 + 2*C, b1 + 2*C, t);
  __syncthreads();
  // P2: ta = tb + relu(tb @ Wlin2 + blin2) ; LN2 -> h3 in ta
  gemmf(tb, Wlin + 2*C*C, o, col, rg);
  {
    float bb = blin[2*C + col];
    #pragma unroll
    for (int r = 0; r < 8; ++r) ta[rg*8 + r][col] = tb[rg*8 + r][col] + fmaxf(o[r] + bb, 0.f);
  }
  __syncthreads();
  ln16f(ta, g2 + 2*C, b2 + 2*C, t);
  __syncthreads();
  // P3: v = h3 @ Wv3 + bv3 -> tb
  gemmf(ta, Wv + 3*C*C, o, col, rg);
  {
    float bb = bv[3*C + col];
    #pragma unroll
    for (int r = 0; r < 8; ++r) tb[rg*8 + r][col] = o[r] + bb;
  }
  __syncthreads();
  // P4: ta = v @ Wo3 + bo3 + h3 ; LN1_3   (each (row,col) of ta read+written by its owner only)
  gemmf(tb, Wo + 3*C*C, o, col, rg);
  {
    float bb = bo[3*C + col];
    #pragma unroll
    for (int r = 0; r < 8; ++r) res[r] = ta[rg*8 + r][col];
    #pragma unroll
    for (int r = 0; r < 8; ++r) ta[rg*8 + r][col] = o[r] + bb + res[r];
  }
  __syncthreads();
  ln16f(ta, g1 + 3*C, b1 + 3*C, t);
  __syncthreads();
  // P5: tb = ta + relu(ta @ Wlin3 + blin3) ; LN2_3
  gemmf(ta, Wlin + 3*C*C, o, col, rg);
  {
    float bb = blin[3*C + col];
    #pragma unroll
    for (int r = 0; r < 8; ++r) tb[rg*8 + r][col] = ta[rg*8 + r][col] + fmaxf(o[r] + bb, 0.f);
  }
  __syncthreads();
  ln16f(tb, g2 + 3*C, b2 + 3*C, t);
  __syncthreads();
  // P6: nan_to_num + store
  for (int idx = t; idx < 16*128; idx += 256){
    int row = idx >> 7, cc = idx & 127;
    if (g0 + row < G){
      float v = tb[row][cc];
      if (isnan(v)) v = 0.f;
      else if (isinf(v)) v = v > 0 ? 3.402823466e38f : -3.402823466e38f;
      out[(size_t)(g0 + row)*C + cc] = v;
    }
  }
}

extern "C" void kernel_launch(void* const* d_in, const int* in_sizes, int n_in,
                              void* d_out, int out_size, void* d_ws, size_t ws_size,
                              hipStream_t stream){
  const float* RF   = (const float*)d_in[0];
  const float* Wq   = (const float*)d_in[1];
  const float* Wk   = (const float*)d_in[2];
  const float* Wv   = (const float*)d_in[3];
  const float* Wo   = (const float*)d_in[4];
  const float* bq   = (const float*)d_in[5];
  const float* bk   = (const float*)d_in[6];
  const float* bv   = (const float*)d_in[7];
  const float* bo   = (const float*)d_in[8];
  const float* Wlin = (const float*)d_in[9];
  const float* blin = (const float*)d_in[10];
  const float* g1   = (const float*)d_in[11];
  const float* b1   = (const float*)d_in[12];
  const float* g2   = (const float*)d_in[13];
  const float* b2   = (const float*)d_in[14];
  const float* seed = (const float*)d_in[15];
  const int* rxn    = (const int*)d_in[16];
  const int* gidx   = (const int*)d_in[17];

  int E = in_sizes[16];
  int G = out_size / C;

  // ws layout
  char* base = (char*)d_ws;
  short* wfrag = (short*)base;                             // 655360 B
  float* qrow  = (float*)(base + 655360);                  // 512 B
  int*   meta  = (int*)(base + 655872);                    // 64 B: [0]=nbins, [1..4]=cnt
  int*   starts= (int*)(base + 655936);                    // 4G
  int*   counts= (int*)(base + 655936 + (size_t)4*G);      // 4G
  int*   gcr   = (int*)(base + 655936 + (size_t)8*G);      // 4G
  int*   binfo = (int*)(base + 655936 + (size_t)12*G);     // 16G
  float* pooled= (float*)(base + 655936 + (size_t)28*G);   // 512G

  hipMemsetAsync(meta, 0, 64, stream);
  hipMemsetAsync(binfo, 0xFF, (size_t)16*G, stream);
  prep_wfrag<<<640, 64, 0, stream>>>(Wq, Wk, Wv, Wo, Wlin, wfrag);
  prep_qrow<<<1, 128, 0, stream>>>(seed, Wq, bq, qrow);
  seg_kernel<<<(G + 255)/256, 256, 0, stream>>>(gidx, E, G, starts, counts, meta + 1, gcr);
  fill_kernel<<<(G + 255)/256, 256, 0, stream>>>(G, meta + 1, gcr, binfo, meta);
  gene_bin_kernel<<<G, 256, 0, stream>>>(RF, wfrag, qrow, bq, bk, bv, bo, blin,
      g1, b1, g2, b2, rxn, starts, counts, binfo, meta, pooled);
  tail_kernel<<<(G + 15)/16, 256, 0, stream>>>(pooled, Wv, Wo, Wlin, bv, bo, blin,
      g1, b1, g2, b2, seed, (float*)d_out, G);
}